// Round 1
// 512.606 us; speedup vs baseline: 1.0272x; 1.0272x over previous
//
#include <hip/hip_runtime.h>
#include <hip/hip_bf16.h>

typedef __hip_bfloat16 bf16;
typedef __attribute__((ext_vector_type(8))) short s8b;   // 8 bf16 (4 VGPRs)
typedef __attribute__((ext_vector_type(4))) short s4b;   // 4 bf16 (8B)
typedef __attribute__((ext_vector_type(4))) float f4;    // MFMA acc

#define BB   32
#define NN   1024
#define FIN  64
#define HEADS 2
#define DH   64
#define HIDD 128
#define SZQ  ((size_t)BB * NN * HIDD)

__device__ __forceinline__ ushort f2bf(float x) {
    bf16 h = __float2bfloat16(x);
    return *(ushort*)&h;
}
__device__ __forceinline__ float bfbits2f(ushort h) {
    union { uint u; float f; } c; c.u = (uint)h << 16; return c.f;
}
__device__ __forceinline__ uint pk_bf16(float lo, float hi) {
    return (uint)f2bf(lo) | ((uint)f2bf(hi) << 16);
}
union U8 { short s[8]; s8b v; };
union U4 { short s[4]; s4b v; };
union UQ { ushort u[8]; s8b v; };

// ---------------------------------------------------------------------------
// Fused setup: [0,1024) prep_w | [1024,1536) transpose/split X |
// [1536,2048) build_q layer 0 | [2048,2560) build_q layer 1.
// ---------------------------------------------------------------------------
__global__ __launch_bounds__(256) void setup_kernel(
        const float* __restrict__ raw, const float* __restrict__ d0,
        const float* __restrict__ d1,
        const float* __restrict__ q0w, const float* __restrict__ k0w,
        const float* __restrict__ v0w, const float* __restrict__ o0w,
        const float* __restrict__ q1w, const float* __restrict__ k1w,
        const float* __restrict__ v1w, const float* __restrict__ o1w,
        ushort* __restrict__ Whi, ushort* __restrict__ Wlo,
        const float* __restrict__ T, const float* __restrict__ theta,
        ushort* __restrict__ Q0hi, ushort* __restrict__ Q0lo,
        ushort* __restrict__ Q1hi, ushort* __restrict__ Q1lo,
        const float* __restrict__ X,
        ushort* __restrict__ XT_hi, ushort* __restrict__ XT_lo) {
    __shared__ float tile[64][65];
    const int bid = blockIdx.x;
    const int t = threadIdx.x;
    if (bid < 1024) {
        int id = bid * 256 + t;
        const float* src; int K, off;
        if      (id <   8192) { src = raw; K =  64; off = 0; }
        else if (id <  16384) { src = d0;  K =  64; off = 8192; }
        else if (id <  32768) { src = d1;  K = 128; off = 16384; }
        else if (id <  65536) { src = q0w; K = 256; off = 32768; }
        else if (id <  98304) { src = k0w; K = 256; off = 65536; }
        else if (id < 131072) { src = v0w; K = 256; off = 98304; }
        else if (id < 147456) { src = o0w; K = 128; off = 131072; }
        else if (id < 180224) { src = q1w; K = 256; off = 147456; }
        else if (id < 212992) { src = k1w; K = 256; off = 180224; }
        else if (id < 245760) { src = v1w; K = 256; off = 212992; }
        else                  { src = o1w; K = 128; off = 245760; }
        int il = id - off;
        int k = il >> 7, c = il & 127;
        float w = src[il];
        ushort h = f2bf(w);
        Whi[off + c * K + k] = h;
        Wlo[off + c * K + k] = f2bf(w - bfbits2f(h));
    } else if (bid < 1536) {
        const int tb = bid - 1024;
        const int b  = tb >> 4;
        const int n0 = (tb & 15) * 64;
        {
            int nl = t >> 2, f0 = (t & 3) * 16;
            const float* xp = X + ((size_t)b * NN + n0 + nl) * 64 + f0;
#pragma unroll
            for (int i = 0; i < 16; i += 4)
                *(float4*)&tile[nl][f0 + i] = *(const float4*)(xp + i);
        }
        __syncthreads();
        {
            int f = t >> 2, n1 = (t & 3) * 16;
            U8 h0, h1, l0, l1;
#pragma unroll
            for (int i = 0; i < 16; i++) {
                float v = tile[n1 + i][f];
                ushort hh = f2bf(v);
                ushort ll = f2bf(v - bfbits2f(hh));
                if (i < 8) { h0.s[i] = (short)hh; l0.s[i] = (short)ll; }
                else       { h1.s[i - 8] = (short)hh; l1.s[i - 8] = (short)ll; }
            }
            size_t gb = ((size_t)b * 64 + f) * NN + n0 + n1;
            *(s8b*)&XT_hi[gb]     = h0.v;  *(s8b*)&XT_hi[gb + 8] = h1.v;
            *(s8b*)&XT_lo[gb]     = l0.v;  *(s8b*)&XT_lo[gb + 8] = l1.v;
        }
    } else {
        const int layer = (bid < 2048) ? 0 : 1;
        ushort* Qhi = layer ? Q1hi : Q0hi;
        ushort* Qlo = layer ? Q1lo : Q0lo;
        float t0 = theta[layer * 3 + 0];
        float t1 = theta[layer * 3 + 1];
        float t2 = theta[layer * 3 + 2];
        float m  = fmaxf(t0, fmaxf(t1, t2));
        float e0 = expf(t0 - m), e1 = expf(t1 - m), e2 = expf(t2 - m);
        float inv = 1.0f / (e0 + e1 + e2);
        e0 *= inv; e1 *= inv; e2 *= inv;
        size_t base = ((size_t)((bid - 1536) & 511) * 256 + t) * 8;
        const float* Tl = T + (size_t)layer * 3 * NN * NN;
        U8 hi, lo;
#pragma unroll
        for (int i = 0; i < 8; i++) {
            float q = e0 * Tl[base + i]
                    + e1 * Tl[base + i + (size_t)NN * NN]
                    + e2 * Tl[base + i + (size_t)2 * NN * NN];
            ushort hh = f2bf(q);
            hi.s[i] = (short)hh;
            lo.s[i] = (short)f2bf(q - bfbits2f(hh));
        }
        *(s8b*)&Qhi[base] = hi.v;
        *(s8b*)&Qlo[base] = lo.v;
    }
}

// ---------------------------------------------------------------------------
// MFMA diffusion: z[b,i,f] = sum_j (Q[i,j]*A[b,i,j]) * h[b,j,f]
// R11: wave tile remap 16xF/2 -> 32xF/4 (B-frag reuse, fewer ds_reads) +
//      XCD-bijective block swizzle (blocks sharing b -> same XCD L2).
// ---------------------------------------------------------------------------
template<int F>
__global__ __launch_bounds__(512, 4) void diffusion_mfma_kernel(
        const ushort* __restrict__ Qhi, const ushort* __restrict__ Qlo,
        const float* __restrict__ A,
        const ushort* __restrict__ hT_hi, const ushort* __restrict__ hT_lo,
        float* __restrict__ z) {
    constexpr int SS  = 72;
    constexpr int NT  = F / 16;
    constexpr int NCW = NT / 4;          // col-tiles per wave (F=64 -> 1, F=128 -> 2)
    __shared__ short Shi[64][SS], Slo[64][SS];
    __shared__ short Hhi[F][SS],  Hlo[F][SS];

    // bijective XCD swizzle: 512 blocks = 8 xcd * 4 b-per-xcd * 16 i0
    const int bidx = blockIdx.x;
    const int u  = bidx >> 3;
    const int b  = (bidx & 7) + 8 * (u >> 4);
    const int i0 = (u & 15) * 64;
    const int t  = threadIdx.x;
    const int w  = t >> 6, lane = t & 63;
    const int quad = lane >> 4, c = lane & 15;
    const int rh = w >> 2;               // 32-row group (0..1)
    const int ch = w & 3;                // col quarter (0..3)

    const int srow = t >> 3, scol = (t & 7) * 8;
    const float*  Ap = A   + ((size_t)b * NN + i0 + srow) * NN + scol;
    const ushort* Qh = Qhi + (size_t)(i0 + srow) * NN + scol;
    const ushort* Ql = Qlo + (size_t)(i0 + srow) * NN + scol;
    constexpr int HTR = 512 / F;
    constexpr int HJ  = 64 / HTR;
    constexpr int HV  = HJ / 8;
    const int hrow = t / HTR, hcol = (t % HTR) * HJ;
    const ushort* Hh = hT_hi + ((size_t)b * F + hrow) * NN + hcol;
    const ushort* Hl = hT_lo + ((size_t)b * F + hrow) * NN + hcol;

    f4 acc[2][NCW];
#pragma unroll
    for (int st = 0; st < 2; st++)
#pragma unroll
        for (int i = 0; i < NCW; i++) acc[st][i] = (f4){0.f, 0.f, 0.f, 0.f};

    float4 a0 = *(const float4*)Ap, a1 = *(const float4*)(Ap + 4);
    s8b hhv[HV], hlv[HV];
#pragma unroll
    for (int vv = 0; vv < HV; vv++) {
        hhv[vv] = *(const s8b*)(Hh + 8 * vv);
        hlv[vv] = *(const s8b*)(Hl + 8 * vv);
    }

#pragma unroll 1
    for (int j0 = 0; j0 < NN; j0 += 64) {
        UQ qh, ql;
        qh.v = *(const s8b*)(Qh + j0);
        ql.v = *(const s8b*)(Ql + j0);
        __syncthreads();
        {
            float av[8] = {a0.x, a0.y, a0.z, a0.w, a1.x, a1.y, a1.z, a1.w};
            U8 hi, lo;
#pragma unroll
            for (int i = 0; i < 8; i++) {
                float q = bfbits2f(qh.u[i]) + bfbits2f(ql.u[i]);
                float s = q * av[i];
                ushort hb = f2bf(s);
                hi.s[i] = (short)hb;
                lo.s[i] = (short)f2bf(s - bfbits2f(hb));
            }
            *(s8b*)&Shi[srow][scol] = hi.v;
            *(s8b*)&Slo[srow][scol] = lo.v;
#pragma unroll
            for (int vv = 0; vv < HV; vv++) {
                *(s8b*)&Hhi[hrow][hcol + 8 * vv] = hhv[vv];
                *(s8b*)&Hlo[hrow][hcol + 8 * vv] = hlv[vv];
            }
        }
        if (j0 + 64 < NN) {
            a0 = *(const float4*)(Ap + j0 + 64);
            a1 = *(const float4*)(Ap + j0 + 68);
#pragma unroll
            for (int vv = 0; vv < HV; vv++) {
                hhv[vv] = *(const s8b*)(Hh + j0 + 64 + 8 * vv);
                hlv[vv] = *(const s8b*)(Hl + j0 + 64 + 8 * vv);
            }
        }
        __syncthreads();

#pragma unroll
        for (int ks = 0; ks < 2; ks++) {
            s8b ah0 = *(const s8b*)&Shi[32 * rh + c][ks * 32 + quad * 8];
            s8b al0 = *(const s8b*)&Slo[32 * rh + c][ks * 32 + quad * 8];
            s8b ah1 = *(const s8b*)&Shi[32 * rh + 16 + c][ks * 32 + quad * 8];
            s8b al1 = *(const s8b*)&Slo[32 * rh + 16 + c][ks * 32 + quad * 8];
#pragma unroll
            for (int ctn = 0; ctn < NCW; ctn++) {
                const int nt = ch * NCW + ctn;
                s8b bhi = *(const s8b*)&Hhi[nt * 16 + c][ks * 32 + quad * 8];
                s8b blo = *(const s8b*)&Hlo[nt * 16 + c][ks * 32 + quad * 8];
                acc[0][ctn] = __builtin_amdgcn_mfma_f32_16x16x32_bf16(ah0, bhi, acc[0][ctn], 0, 0, 0);
                acc[0][ctn] = __builtin_amdgcn_mfma_f32_16x16x32_bf16(al0, bhi, acc[0][ctn], 0, 0, 0);
                acc[0][ctn] = __builtin_amdgcn_mfma_f32_16x16x32_bf16(ah0, blo, acc[0][ctn], 0, 0, 0);
                acc[1][ctn] = __builtin_amdgcn_mfma_f32_16x16x32_bf16(ah1, bhi, acc[1][ctn], 0, 0, 0);
                acc[1][ctn] = __builtin_amdgcn_mfma_f32_16x16x32_bf16(al1, bhi, acc[1][ctn], 0, 0, 0);
                acc[1][ctn] = __builtin_amdgcn_mfma_f32_16x16x32_bf16(ah1, blo, acc[1][ctn], 0, 0, 0);
            }
        }
    }
#pragma unroll
    for (int st = 0; st < 2; st++)
#pragma unroll
        for (int ctn = 0; ctn < NCW; ctn++)
#pragma unroll
            for (int r = 0; r < 4; r++)
                z[((size_t)b * NN + i0 + 32 * rh + 16 * st + quad * 4 + r) * F
                  + (ch * NCW + ctn) * 16 + c] = acc[st][ctn][r];
}

// ---------------------------------------------------------------------------
// MFMA dense GEMM, split-precision bf16.
// R11: wave tile remap 16 rows x CB cols -> 32 rows x CB/2 cols. Same MFMA
// count & acc registers, but each B-fragment feeds 2 row-tiles: ds_read_b128
// per wave per K-step drops 26->16 (CB=192) / 18->12 (CB=128).
// OMODE 0: fp32 out. 1: qkv bf16 (q,k row-major; V transposed). 2: fp32 +
// transposed split. 3: fused out-proj + residual + final classifier.
// ---------------------------------------------------------------------------
template<int K1, int K2, int CB, bool RELU, bool RESID, int OMODE>
__global__ __launch_bounds__(256) void dense_mfma_kernel(
        const float* __restrict__ in1, const float* __restrict__ in2,
        const ushort* __restrict__ WT_hi, const ushort* __restrict__ WT_lo,
        const float* __restrict__ bias, const float* __restrict__ biask,
        const float* __restrict__ biasv,
        float* __restrict__ out, ushort* __restrict__ outq,
        ushort* __restrict__ hiT, ushort* __restrict__ loT,
        const float* __restrict__ Wfin, const float* __restrict__ bfin,
        float* __restrict__ fout) {
    constexpr int KD  = K1 + K2;
    constexpr int NKT = KD / 32;
    constexpr int NCH = CB / 32;       // col-tiles per wave
    __shared__ short Xhi[64][40], Xlo[64][40];
    __shared__ short Whi[CB][40], Wlo[CB][40];
    __shared__ float red[64][2];       // OMODE3 cross-wave reduction

    const int r0 = blockIdx.x * 64;
    const int c0 = blockIdx.y * CB;
    const int t  = threadIdx.x;
    const int w  = t >> 6, lane = t & 63;
    const int quad = lane >> 4, c = lane & 15;
    const int rh = w >> 1;             // 32-row group (0..1)
    const int ch = w & 1;              // col half (0..1)

    f4 acc[2][NCH];
#pragma unroll
    for (int st = 0; st < 2; st++)
#pragma unroll
        for (int i = 0; i < NCH; i++) acc[st][i] = (f4){0.f, 0.f, 0.f, 0.f};

    for (int kt = 0; kt < NKT; kt++) {
        const int k0 = kt * 32;
        __syncthreads();
        {
            int row = t >> 2, kk = (t & 3) * 8;
            int g = r0 + row;
            const float* p;
            if (K2 > 0) {
                int k = k0 + kk;
                p = (k < K1) ? (in1 + (size_t)g * K1 + k)
                             : (in2 + (size_t)g * K2 + (k - K1));
            } else {
                p = in1 + (size_t)g * K1 + k0 + kk;
            }
            float4 a = *(const float4*)p, bq = *(const float4*)(p + 4);
            float sv[8] = {a.x, a.y, a.z, a.w, bq.x, bq.y, bq.z, bq.w};
            U8 hi, lo;
#pragma unroll
            for (int i = 0; i < 8; i++) {
                ushort hh = f2bf(sv[i]);
                hi.s[i] = (short)hh;
                lo.s[i] = (short)f2bf(sv[i] - bfbits2f(hh));
            }
            *(s8b*)&Xhi[row][kk] = hi.v;
            *(s8b*)&Xlo[row][kk] = lo.v;
        }
        {
#pragma unroll
            for (int p = 0; p < CB / 64; p++) {
                int cc = p * 64 + (t >> 2), kk = (t & 3) * 8;
                size_t gsrc = (size_t)(c0 + cc) * KD + k0 + kk;
                *(s8b*)&Whi[cc][kk] = *(const s8b*)&WT_hi[gsrc];
                *(s8b*)&Wlo[cc][kk] = *(const s8b*)&WT_lo[gsrc];
            }
        }
        __syncthreads();

        s8b ah0 = *(const s8b*)&Xhi[32 * rh + c][quad * 8];
        s8b al0 = *(const s8b*)&Xlo[32 * rh + c][quad * 8];
        s8b ah1 = *(const s8b*)&Xhi[32 * rh + 16 + c][quad * 8];
        s8b al1 = *(const s8b*)&Xlo[32 * rh + 16 + c][quad * 8];
#pragma unroll
        for (int ct = 0; ct < NCH; ct++) {
            s8b bh = *(const s8b*)&Whi[ch * (CB / 2) + ct * 16 + c][quad * 8];
            s8b bl = *(const s8b*)&Wlo[ch * (CB / 2) + ct * 16 + c][quad * 8];
            acc[0][ct] = __builtin_amdgcn_mfma_f32_16x16x32_bf16(ah0, bh, acc[0][ct], 0, 0, 0);
            acc[0][ct] = __builtin_amdgcn_mfma_f32_16x16x32_bf16(al0, bh, acc[0][ct], 0, 0, 0);
            acc[0][ct] = __builtin_amdgcn_mfma_f32_16x16x32_bf16(ah0, bl, acc[0][ct], 0, 0, 0);
            acc[1][ct] = __builtin_amdgcn_mfma_f32_16x16x32_bf16(ah1, bh, acc[1][ct], 0, 0, 0);
            acc[1][ct] = __builtin_amdgcn_mfma_f32_16x16x32_bf16(al1, bh, acc[1][ct], 0, 0, 0);
            acc[1][ct] = __builtin_amdgcn_mfma_f32_16x16x32_bf16(ah1, bl, acc[1][ct], 0, 0, 0);
        }
    }

    if (OMODE == 3) {
        float fc[2][2][4];
#pragma unroll
        for (int st = 0; st < 2; st++)
#pragma unroll
            for (int o = 0; o < 2; o++)
#pragma unroll
                for (int r = 0; r < 4; r++) fc[st][o][r] = 0.f;
#pragma unroll
        for (int ct = 0; ct < NCH; ct++) {
            const int col = c0 + ch * (CB / 2) + ct * 16 + c;
            float bv = bias[col];
            float w0 = Wfin[col * 2], w1 = Wfin[col * 2 + 1];
#pragma unroll
            for (int st = 0; st < 2; st++) {
                const int rg = r0 + 32 * rh + 16 * st + quad * 4;
#pragma unroll
                for (int r = 0; r < 4; r++) {
                    float v = acc[st][ct][r] + bv;
                    if (RELU) v = fmaxf(v, 0.f);
                    if (RESID) v += out[(size_t)(rg + r) * 128 + col];
                    fc[st][0][r] += v * w0;
                    fc[st][1][r] += v * w1;
                }
            }
        }
#pragma unroll
        for (int st = 0; st < 2; st++)
#pragma unroll
            for (int r = 0; r < 4; r++) {
                float a0 = fc[st][0][r], a1 = fc[st][1][r];
#pragma unroll
                for (int off = 1; off < 16; off <<= 1) {
                    a0 += __shfl_xor(a0, off, 16);
                    a1 += __shfl_xor(a1, off, 16);
                }
                fc[st][0][r] = a0; fc[st][1][r] = a1;
            }
        if (ch == 1 && c == 0) {
#pragma unroll
            for (int st = 0; st < 2; st++)
#pragma unroll
                for (int r = 0; r < 4; r++) {
                    int lr = 32 * rh + 16 * st + quad * 4 + r;
                    red[lr][0] = fc[st][0][r];
                    red[lr][1] = fc[st][1][r];
                }
        }
        __syncthreads();
        if (ch == 0 && c == 0) {
#pragma unroll
            for (int st = 0; st < 2; st++)
#pragma unroll
                for (int r = 0; r < 4; r++) {
                    int lr = 32 * rh + 16 * st + quad * 4 + r;
                    size_t row = (size_t)r0 + lr;
                    fout[row * 2]     = fc[st][0][r] + red[lr][0] + bfin[0];
                    fout[row * 2 + 1] = fc[st][1][r] + red[lr][1] + bfin[1];
                }
        }
        return;
    }
#pragma unroll
    for (int st = 0; st < 2; st++) {
        const int row_g0 = r0 + 32 * rh + 16 * st + quad * 4;
#pragma unroll
        for (int ct = 0; ct < NCH; ct++) {
            const int col = c0 + ch * (CB / 2) + ct * 16 + c;
            if (OMODE == 1) {
                int tensor = col >> 7, cc2 = col & 127;
                float bv = (tensor == 0 ? bias : tensor == 1 ? biask : biasv)[cc2];
                int head = cc2 >> 6, d = cc2 & 63;
                int b = row_g0 >> 10, n = row_g0 & 1023;
                if (tensor == 2) {
                    // V^T [B,H,64,N]: 4 consecutive n -> one 8B packed store
                    U4 pk;
#pragma unroll
                    for (int r = 0; r < 4; r++) pk.s[r] = (short)f2bf(acc[st][ct][r] + bv);
                    size_t addr = (((size_t)b * HEADS + head) * 64 + d) * NN + n;
                    *(s4b*)&outq[2 * SZQ + addr] = pk.v;
                } else {
                    ushort* dst = outq + (size_t)tensor * SZQ
                                + (((size_t)b * HEADS + head) * NN + n) * 64 + d;
#pragma unroll
                    for (int r = 0; r < 4; r++) dst[(size_t)r * 64] = f2bf(acc[st][ct][r] + bv);
                }
            } else {
                float bv = bias[col];
                float vv[4];
#pragma unroll
                for (int r = 0; r < 4; r++) {
                    float v = acc[st][ct][r] + bv;
                    if (RELU) v = fmaxf(v, 0.f);
                    size_t o = (size_t)(row_g0 + r) * 128 + col;
                    if (RESID) v += out[o];
                    out[o] = v;
                    vv[r] = v;
                }
                if (OMODE == 2) {
                    int b = row_g0 >> 10, n = row_g0 & 1023;
                    U4 ph, pl;
#pragma unroll
                    for (int r = 0; r < 4; r++) {
                        ushort hh = f2bf(vv[r]);
                        ph.s[r] = (short)hh;
                        pl.s[r] = (short)f2bf(vv[r] - bfbits2f(hh));
                    }
                    size_t tb = ((size_t)b * 128 + col) * NN + n;
                    *(s4b*)&hiT[tb] = ph.v;
                    *(s4b*)&loT[tb] = pl.v;
                }
            }
        }
    }
}

// ---------------------------------------------------------------------------
// MFMA flash attention v4 + R11 XCD swizzle: the 16 blocks sharing one
// (b,h) K/V panel (256KB) now land on the same XCD's L2.
// ---------------------------------------------------------------------------
__global__ __launch_bounds__(256) void attn_mfma_kernel(const ushort* __restrict__ q,
                                                        const ushort* __restrict__ k,
                                                        const ushort* __restrict__ vt,
                                                        float* __restrict__ ctx) {
    __shared__ short Ks[128][72];
    __shared__ short Vt[64][136];

    // bijective XCD swizzle: 1024 blocks = 8 xcd * 8 bh-per-xcd * 16 n0
    const int bidx = blockIdx.x;
    const int u  = bidx >> 3;
    const int bh = (bidx & 7) + 8 * (u >> 4);
    const int n0 = (u & 15) * 64;
    const int b  = bh >> 1, h = bh & 1;
    const int t  = threadIdx.x;
    const int w  = t >> 6;
    const int lane = t & 63;
    const int quad = lane >> 4, c = lane & 15;
    const size_t kvbase = (size_t)bh * NN * 64;   // same elem count for k and vt
    const float scale = 0.125f;

    s8b qf0, qf1;
    {
        const ushort* qrow = q + kvbase + (size_t)(n0 + 16 * w + c) * 64;
        qf0 = *(const s8b*)(qrow + quad * 8);
        qf1 = *(const s8b*)(qrow + 32 + quad * 8);
    }

    f4 O[4];
#pragma unroll
    for (int i = 0; i < 4; i++) O[i] = (f4){0.f, 0.f, 0.f, 0.f};
    float l_i = 0.f;

    for (int kt0 = 0; kt0 < NN; kt0 += 128) {
        __syncthreads();
        {   // K: 128 keys row-major, 4 b128 per thread
            int key = t >> 2, d0 = (t & 3) * 16;
#pragma unroll
            for (int half = 0; half < 2; half++) {
                const ushort* kr = k + kvbase + (size_t)(kt0 + 64 * half + key) * 64 + d0;
                *(s8b*)&Ks[64 * half + key][d0]     = *(const s8b*)kr;
                *(s8b*)&Ks[64 * half + key][d0 + 8] = *(const s8b*)(kr + 8);
            }
            // V^T: row d = t>>2, cols (t&3)*32..+31, 4 b128 copies
            int d = t >> 2, ch = (t & 3) * 32;
            const ushort* vr = vt + kvbase + (size_t)d * NN + kt0 + ch;
            *(s8b*)&Vt[d][ch]      = *(const s8b*)vr;
            *(s8b*)&Vt[d][ch + 8]  = *(const s8b*)(vr + 8);
            *(s8b*)&Vt[d][ch + 16] = *(const s8b*)(vr + 16);
            *(s8b*)&Vt[d][ch + 24] = *(const s8b*)(vr + 24);
        }
        __syncthreads();

        // ---- S for 4 groups of 32 keys ----
        f4 sg[4][2];
#pragma unroll
        for (int g = 0; g < 4; g++) {
            const int kb = g * 32;
            sg[g][0] = (f4){0.f, 0.f, 0.f, 0.f};
            sg[g][1] = (f4){0.f, 0.f, 0.f, 0.f};
#pragma unroll
            for (int ch = 0; ch < 2; ch++) {
                s8b ka = *(const s8b*)&Ks[kb + c][ch * 32 + quad * 8];
                s8b kB = *(const s8b*)&Ks[kb + 16 + c][ch * 32 + quad * 8];
                s8b qf = ch ? qf1 : qf0;
                sg[g][0] = __builtin_amdgcn_mfma_f32_16x16x32_bf16(ka, qf, sg[g][0], 0, 0, 0);
                sg[g][1] = __builtin_amdgcn_mfma_f32_16x16x32_bf16(kB, qf, sg[g][1], 0, 0, 0);
            }
        }
        // ---- softmax numerator without running max ----
        float pv[4][8];
        float ps = 0.f;
#pragma unroll
        for (int g = 0; g < 4; g++)
#pragma unroll
            for (int r = 0; r < 4; r++) {
                pv[g][r]     = __expf(sg[g][0][r] * scale);
                pv[g][4 + r] = __expf(sg[g][1][r] * scale);
                ps += pv[g][r] + pv[g][4 + r];
            }
        ps += __shfl_xor(ps, 16);
        ps += __shfl_xor(ps, 32);
        l_i += ps;

        // ---- P transpose + PV per group ----
        int addr0 = ((((2 * quad) & 3) << 4) | c) << 2;
        int addr1 = ((((2 * quad + 1) & 3) << 4) | c) << 2;
        int tsel = quad >> 1;
#pragma unroll
        for (int g = 0; g < 4; g++) {
            const int kb = g * 32;
            uint Da01 = pk_bf16(pv[g][0], pv[g][1]), Da23 = pk_bf16(pv[g][2], pv[g][3]);
            uint Db01 = pk_bf16(pv[g][4], pv[g][5]), Db23 = pk_bf16(pv[g][6], pv[g][7]);
            int A01_0 = __builtin_amdgcn_ds_bpermute(addr0, (int)Da01);
            int A23_0 = __builtin_amdgcn_ds_bpermute(addr0, (int)Da23);
            int B01_0 = __builtin_amdgcn_ds_bpermute(addr0, (int)Db01);
            int B23_0 = __builtin_amdgcn_ds_bpermute(addr0, (int)Db23);
            int A01_1 = __builtin_amdgcn_ds_bpermute(addr1, (int)Da01);
            int A23_1 = __builtin_amdgcn_ds_bpermute(addr1, (int)Da23);
            int B01_1 = __builtin_amdgcn_ds_bpermute(addr1, (int)Db01);
            int B23_1 = __builtin_amdgcn_ds_bpermute(addr1, (int)Db23);
            union { int i[4]; s8b s; } pf;
            pf.i[0] = tsel ? B01_0 : A01_0;
            pf.i[1] = tsel ? B23_0 : A23_0;
            pf.i[2] = tsel ? B01_1 : A01_1;
            pf.i[3] = tsel ? B23_1 : A23_1;
#pragma unroll
            for (int dt = 0; dt < 4; dt++) {
                s8b vf = *(const s8b*)&Vt[16 * dt + c][kb + quad * 8];
                O[dt] = __builtin_amdgcn_mfma_f32_16x16x32_bf16(vf, pf.s, O[dt], 0, 0, 0);
            }
        }
    }

    float inv = 1.0f / l_i;
    float* crow = ctx + ((size_t)b * NN + n0 + 16 * w + c) * HIDD + h * DH;
#pragma unroll
    for (int dt = 0; dt < 4; dt++)
#pragma unroll
        for (int r = 0; r < 4; r++)
            crow[16 * dt + 4 * quad + r] = O[dt][r] * inv;
}

// ---------------------------------------------------------------------------
extern "C" void kernel_launch(void* const* d_in, const int* in_sizes, int n_in,
                              void* d_out, int out_size, void* d_ws, size_t ws_size,
                              hipStream_t stream) {
    (void)in_sizes; (void)n_in; (void)out_size; (void)ws_size;
    const float* X     = (const float*)d_in[0];
    const float* A     = (const float*)d_in[1];
    const float* T     = (const float*)d_in[2];
    const float* theta = (const float*)d_in[3];
    const float* W_raw = (const float*)d_in[4];
    const float* b_raw = (const float*)d_in[5];
    const float* Wd0   = (const float*)d_in[6];
    const float* bd0   = (const float*)d_in[7];
    const float* Wd1   = (const float*)d_in[8];
    const float* bd1   = (const float*)d_in[9];
    const float* W_fin = (const float*)d_in[10];
    const float* b_fin = (const float*)d_in[11];
    const float* Wq0 = (const float*)d_in[12]; const float* bq0 = (const float*)d_in[13];
    const float* Wk0 = (const float*)d_in[14]; const float* bk0 = (const float*)d_in[15];
    const float* Wv0 = (const float*)d_in[16]; const float* bv0 = (const float*)d_in[17];
    const float* Wo0 = (const float*)d_in[18]; const float* bo0 = (const float*)d_in[19];
    const float* Wq1 = (const float*)d_in[20]; const float* bq1 = (const float*)d_in[21];
    const float* Wk1 = (const float*)d_in[22]; const float* bk1 = (const float*)d_in[23];
    const float* Wv1 = (const float*)d_in[24]; const float* bv1 = (const float*)d_in[25];
    const float* Wo1 = (const float*)d_in[26]; const float* bo1 = (const float*)d_in[27];

    float* ws   = (float*)d_ws;
    const size_t SZ = (size_t)BB * NN * HIDD;
    ushort* Q0hi = (ushort*)ws;
    ushort* Q0lo = Q0hi + (size_t)NN * NN;
    float* hp   = ws + (size_t)NN * NN;
    float* h    = hp + SZ;
    float* z    = h + SZ;
    ushort* qb  = (ushort*)(z + SZ);          // q | k | v^T contiguous (3*SZ)
    ushort* kb  = qb + SZ;
    ushort* XT_hi = qb + 3 * SZ;
    ushort* XT_lo = XT_hi + SZ / 2;
    ushort* hT_hi = XT_lo + SZ / 2;
    ushort* hT_lo = hT_hi + SZ;
    ushort* WT_hi = hT_lo + SZ;
    ushort* WT_lo = WT_hi + 262144;
    ushort* Q1hi = WT_lo + 262144;
    ushort* Q1lo = Q1hi + (size_t)NN * NN;

    const int OFF_RAW = 0, OFF_D0 = 8192, OFF_D1 = 16384, OFF_QKV0 = 32768,
              OFF_O0 = 131072, OFF_QKV1 = 147456, OFF_O1 = 245760;

    const int attnGrid = BB * HEADS * (NN / 64);
    const int diffGrid = BB * (NN / 64);
    const dim3 dg1(512, 1), dg2(512, 2);

    // fused prep_w + X transpose/split + build_q layers 0 AND 1
    setup_kernel<<<2560, 256, 0, stream>>>(W_raw, Wd0, Wd1, Wq0, Wk0, Wv0, Wo0,
                                           Wq1, Wk1, Wv1, Wo1, WT_hi, WT_lo,
                                           T, theta, Q0hi, Q0lo, Q1hi, Q1lo,
                                           X, XT_hi, XT_lo);

    // ---- layer 0 ----
    dense_mfma_kernel<64, 0, 128, false, false, 0><<<dg1, 256, 0, stream>>>(
        X, nullptr, WT_hi + OFF_RAW, WT_lo + OFF_RAW, b_raw, nullptr, nullptr,
        hp, nullptr, nullptr, nullptr, nullptr, nullptr, nullptr);
    diffusion_mfma_kernel<64><<<diffGrid, 512, 0, stream>>>(Q0hi, Q0lo, A, XT_hi, XT_lo, z);
    dense_mfma_kernel<64, 0, 128, true, false, 2><<<dg1, 256, 0, stream>>>(
        z, nullptr, WT_hi + OFF_D0, WT_lo + OFF_D0, bd0, nullptr, nullptr,
        h, nullptr, hT_hi, hT_lo, nullptr, nullptr, nullptr);
    dense_mfma_kernel<128, 128, 192, false, false, 1><<<dg2, 256, 0, stream>>>(
        h, hp, WT_hi + OFF_QKV0, WT_lo + OFF_QKV0, bq0, bk0, bv0,
        nullptr, qb, nullptr, nullptr, nullptr, nullptr, nullptr);
    attn_mfma_kernel<<<attnGrid, 256, 0, stream>>>(qb, kb, qb + 2 * SZ, z);
    dense_mfma_kernel<128, 0, 128, true, false, 0><<<dg1, 256, 0, stream>>>(
        z, nullptr, WT_hi + OFF_O0, WT_lo + OFF_O0, bo0, nullptr, nullptr,
        hp, nullptr, nullptr, nullptr, nullptr, nullptr, nullptr);

    // ---- layer 1 ----
    diffusion_mfma_kernel<128><<<diffGrid, 512, 0, stream>>>(Q1hi, Q1lo, A, hT_hi, hT_lo, z);
    dense_mfma_kernel<128, 0, 128, true, false, 0><<<dg1, 256, 0, stream>>>(
        z, nullptr, WT_hi + OFF_D1, WT_lo + OFF_D1, bd1, nullptr, nullptr,
        h, nullptr, nullptr, nullptr, nullptr, nullptr, nullptr);
    dense_mfma_kernel<128, 128, 192, false, false, 1><<<dg2, 256, 0, stream>>>(
        h, hp, WT_hi + OFF_QKV1, WT_lo + OFF_QKV1, bq1, bk1, bv1,
        nullptr, qb, nullptr, nullptr, nullptr, nullptr, nullptr);
    attn_mfma_kernel<<<attnGrid, 256, 0, stream>>>(qb, kb, qb + 2 * SZ, z);
    dense_mfma_kernel<128, 0, 128, true, true, 3><<<dg1, 256, 0, stream>>>(
        z, nullptr, WT_hi + OFF_O1, WT_lo + OFF_O1, bo1, nullptr, nullptr,
        hp, nullptr, nullptr, nullptr, W_fin, b_fin, (float*)d_out);
}

// Round 2
// 505.581 us; speedup vs baseline: 1.0414x; 1.0139x over previous
//
#include <hip/hip_runtime.h>
#include <hip/hip_bf16.h>

typedef __hip_bfloat16 bf16;
typedef __attribute__((ext_vector_type(8))) short s8b;   // 8 bf16 (4 VGPRs)
typedef __attribute__((ext_vector_type(4))) short s4b;   // 4 bf16 (8B)
typedef __attribute__((ext_vector_type(4))) float f4;    // MFMA acc

#define BB   32
#define NN   1024
#define FIN  64
#define HEADS 2
#define DH   64
#define HIDD 128
#define SZQ  ((size_t)BB * NN * HIDD)

__device__ __forceinline__ ushort f2bf(float x) {
    bf16 h = __float2bfloat16(x);
    return *(ushort*)&h;
}
__device__ __forceinline__ float bfbits2f(ushort h) {
    union { uint u; float f; } c; c.u = (uint)h << 16; return c.f;
}
__device__ __forceinline__ uint pk_bf16(float lo, float hi) {
    return (uint)f2bf(lo) | ((uint)f2bf(hi) << 16);
}
union U8 { short s[8]; s8b v; };
union U4 { short s[4]; s4b v; };
union UQ { ushort u[8]; s8b v; };

// ---------------------------------------------------------------------------
// Fused setup: [0,1024) prep_w | [1024,1536) transpose/split X |
// [1536,2048) build_q layer 0 | [2048,2560) build_q layer 1.
// ---------------------------------------------------------------------------
__global__ __launch_bounds__(256) void setup_kernel(
        const float* __restrict__ raw, const float* __restrict__ d0,
        const float* __restrict__ d1,
        const float* __restrict__ q0w, const float* __restrict__ k0w,
        const float* __restrict__ v0w, const float* __restrict__ o0w,
        const float* __restrict__ q1w, const float* __restrict__ k1w,
        const float* __restrict__ v1w, const float* __restrict__ o1w,
        ushort* __restrict__ Whi, ushort* __restrict__ Wlo,
        const float* __restrict__ T, const float* __restrict__ theta,
        ushort* __restrict__ Q0hi, ushort* __restrict__ Q0lo,
        ushort* __restrict__ Q1hi, ushort* __restrict__ Q1lo,
        const float* __restrict__ X,
        ushort* __restrict__ XT_hi, ushort* __restrict__ XT_lo) {
    __shared__ float tile[64][65];
    const int bid = blockIdx.x;
    const int t = threadIdx.x;
    if (bid < 1024) {
        int id = bid * 256 + t;
        const float* src; int K, off;
        if      (id <   8192) { src = raw; K =  64; off = 0; }
        else if (id <  16384) { src = d0;  K =  64; off = 8192; }
        else if (id <  32768) { src = d1;  K = 128; off = 16384; }
        else if (id <  65536) { src = q0w; K = 256; off = 32768; }
        else if (id <  98304) { src = k0w; K = 256; off = 65536; }
        else if (id < 131072) { src = v0w; K = 256; off = 98304; }
        else if (id < 147456) { src = o0w; K = 128; off = 131072; }
        else if (id < 180224) { src = q1w; K = 256; off = 147456; }
        else if (id < 212992) { src = k1w; K = 256; off = 180224; }
        else if (id < 245760) { src = v1w; K = 256; off = 212992; }
        else                  { src = o1w; K = 128; off = 245760; }
        int il = id - off;
        int k = il >> 7, c = il & 127;
        float w = src[il];
        ushort h = f2bf(w);
        Whi[off + c * K + k] = h;
        Wlo[off + c * K + k] = f2bf(w - bfbits2f(h));
    } else if (bid < 1536) {
        const int tb = bid - 1024;
        const int b  = tb >> 4;
        const int n0 = (tb & 15) * 64;
        {
            int nl = t >> 2, f0 = (t & 3) * 16;
            const float* xp = X + ((size_t)b * NN + n0 + nl) * 64 + f0;
#pragma unroll
            for (int i = 0; i < 16; i += 4)
                *(float4*)&tile[nl][f0 + i] = *(const float4*)(xp + i);
        }
        __syncthreads();
        {
            int f = t >> 2, n1 = (t & 3) * 16;
            U8 h0, h1, l0, l1;
#pragma unroll
            for (int i = 0; i < 16; i++) {
                float v = tile[n1 + i][f];
                ushort hh = f2bf(v);
                ushort ll = f2bf(v - bfbits2f(hh));
                if (i < 8) { h0.s[i] = (short)hh; l0.s[i] = (short)ll; }
                else       { h1.s[i - 8] = (short)hh; l1.s[i - 8] = (short)ll; }
            }
            size_t gb = ((size_t)b * 64 + f) * NN + n0 + n1;
            *(s8b*)&XT_hi[gb]     = h0.v;  *(s8b*)&XT_hi[gb + 8] = h1.v;
            *(s8b*)&XT_lo[gb]     = l0.v;  *(s8b*)&XT_lo[gb + 8] = l1.v;
        }
    } else {
        const int layer = (bid < 2048) ? 0 : 1;
        ushort* Qhi = layer ? Q1hi : Q0hi;
        ushort* Qlo = layer ? Q1lo : Q0lo;
        float t0 = theta[layer * 3 + 0];
        float t1 = theta[layer * 3 + 1];
        float t2 = theta[layer * 3 + 2];
        float m  = fmaxf(t0, fmaxf(t1, t2));
        float e0 = expf(t0 - m), e1 = expf(t1 - m), e2 = expf(t2 - m);
        float inv = 1.0f / (e0 + e1 + e2);
        e0 *= inv; e1 *= inv; e2 *= inv;
        size_t base = ((size_t)((bid - 1536) & 511) * 256 + t) * 8;
        const float* Tl = T + (size_t)layer * 3 * NN * NN;
        U8 hi, lo;
#pragma unroll
        for (int i = 0; i < 8; i++) {
            float q = e0 * Tl[base + i]
                    + e1 * Tl[base + i + (size_t)NN * NN]
                    + e2 * Tl[base + i + (size_t)2 * NN * NN];
            ushort hh = f2bf(q);
            hi.s[i] = (short)hh;
            lo.s[i] = (short)f2bf(q - bfbits2f(hh));
        }
        *(s8b*)&Qhi[base] = hi.v;
        *(s8b*)&Qlo[base] = lo.v;
    }
}

// ---------------------------------------------------------------------------
// R12 fused diffusion + post-dense:
//   z[b,i,f] = sum_j (Q[i,j]*A[b,i,j]) * h[b,j,f]   (phase 1, in-register)
//   h_out    = relu(z @ Wd + bd)                    (phase 3, z via LDS only)
// z never touches HBM (was 2x16.8MB write+read + a full launch per layer).
// Accumulation order matches the old separate kernels exactly -> bit-identical.
// WRITE_HT additionally emits split-transposed h (layer-0 path).
// ---------------------------------------------------------------------------
template<int F, bool WRITE_HT>
__global__ __launch_bounds__(512, 4) void diff_dense_kernel(
        const ushort* __restrict__ Qhi, const ushort* __restrict__ Qlo,
        const float* __restrict__ A,
        const ushort* __restrict__ hT_hi, const ushort* __restrict__ hT_lo,
        const ushort* __restrict__ WT_hi, const ushort* __restrict__ WT_lo,
        const float* __restrict__ bias,
        float* __restrict__ hout,
        ushort* __restrict__ hiT, ushort* __restrict__ loT) {
    constexpr int SS  = 72;
    constexpr int NT  = F / 16;
    constexpr int NCW = NT / 4;          // col-tiles per wave in phase 1
    constexpr int SZ2 = F + 8;           // Z LDS stride (shorts)
    constexpr int P1 = 2 * 64 * SS + 2 * F * SS;
    constexpr int P2 = 2 * 64 * SZ2 + 2 * 128 * 40;
    __shared__ short smem[(P1 > P2) ? P1 : P2];
    short* Shi = smem;                   // [64][SS]
    short* Slo = Shi + 64 * SS;
    short* Hhi = Slo + 64 * SS;          // [F][SS]
    short* Hlo = Hhi + (size_t)F * SS;
    short* Zhi = smem;                   // [64][SZ2]  (aliases S/H after phase 1)
    short* Zlo = Zhi + 64 * SZ2;
    short* Wsh = Zlo + 64 * SZ2;         // [128][40]
    short* Wsl = Wsh + 128 * 40;

    // bijective XCD swizzle: 512 blocks = 8 xcd * 4 b-per-xcd * 16 i0
    const int bidx = blockIdx.x;
    const int u  = bidx >> 3;
    const int b  = (bidx & 7) + 8 * (u >> 4);
    const int i0 = (u & 15) * 64;
    const int t  = threadIdx.x;
    const int w  = t >> 6, lane = t & 63;
    const int quad = lane >> 4, c = lane & 15;
    const int rh = w >> 2;               // 32-row group (0..1)
    const int ch = w & 3;                // col quarter (0..3)

    const int srow = t >> 3, scol = (t & 7) * 8;
    const float*  Ap = A   + ((size_t)b * NN + i0 + srow) * NN + scol;
    const ushort* Qh = Qhi + (size_t)(i0 + srow) * NN + scol;
    const ushort* Ql = Qlo + (size_t)(i0 + srow) * NN + scol;
    constexpr int HTR = 512 / F;
    constexpr int HJ  = 64 / HTR;
    constexpr int HV  = HJ / 8;
    const int hrow = t / HTR, hcol = (t % HTR) * HJ;
    const ushort* Hh = hT_hi + ((size_t)b * F + hrow) * NN + hcol;
    const ushort* Hl = hT_lo + ((size_t)b * F + hrow) * NN + hcol;

    f4 acc[2][NCW];
#pragma unroll
    for (int st = 0; st < 2; st++)
#pragma unroll
        for (int i = 0; i < NCW; i++) acc[st][i] = (f4){0.f, 0.f, 0.f, 0.f};

    float4 a0 = *(const float4*)Ap, a1 = *(const float4*)(Ap + 4);
    s8b hhv[HV], hlv[HV];
#pragma unroll
    for (int vv = 0; vv < HV; vv++) {
        hhv[vv] = *(const s8b*)(Hh + 8 * vv);
        hlv[vv] = *(const s8b*)(Hl + 8 * vv);
    }

#pragma unroll 1
    for (int j0 = 0; j0 < NN; j0 += 64) {
        UQ qh, ql;
        qh.v = *(const s8b*)(Qh + j0);
        ql.v = *(const s8b*)(Ql + j0);
        __syncthreads();
        {
            float av[8] = {a0.x, a0.y, a0.z, a0.w, a1.x, a1.y, a1.z, a1.w};
            U8 hi, lo;
#pragma unroll
            for (int i = 0; i < 8; i++) {
                float q = bfbits2f(qh.u[i]) + bfbits2f(ql.u[i]);
                float s = q * av[i];
                ushort hb = f2bf(s);
                hi.s[i] = (short)hb;
                lo.s[i] = (short)f2bf(s - bfbits2f(hb));
            }
            *(s8b*)&Shi[srow * SS + scol] = hi.v;
            *(s8b*)&Slo[srow * SS + scol] = lo.v;
#pragma unroll
            for (int vv = 0; vv < HV; vv++) {
                *(s8b*)&Hhi[hrow * SS + hcol + 8 * vv] = hhv[vv];
                *(s8b*)&Hlo[hrow * SS + hcol + 8 * vv] = hlv[vv];
            }
        }
        if (j0 + 64 < NN) {
            a0 = *(const float4*)(Ap + j0 + 64);
            a1 = *(const float4*)(Ap + j0 + 68);
#pragma unroll
            for (int vv = 0; vv < HV; vv++) {
                hhv[vv] = *(const s8b*)(Hh + j0 + 64 + 8 * vv);
                hlv[vv] = *(const s8b*)(Hl + j0 + 64 + 8 * vv);
            }
        }
        __syncthreads();

#pragma unroll
        for (int ks = 0; ks < 2; ks++) {
            s8b ah0 = *(const s8b*)&Shi[(32 * rh + c) * SS + ks * 32 + quad * 8];
            s8b al0 = *(const s8b*)&Slo[(32 * rh + c) * SS + ks * 32 + quad * 8];
            s8b ah1 = *(const s8b*)&Shi[(32 * rh + 16 + c) * SS + ks * 32 + quad * 8];
            s8b al1 = *(const s8b*)&Slo[(32 * rh + 16 + c) * SS + ks * 32 + quad * 8];
#pragma unroll
            for (int ctn = 0; ctn < NCW; ctn++) {
                const int nt = ch * NCW + ctn;
                s8b bhi = *(const s8b*)&Hhi[(nt * 16 + c) * SS + ks * 32 + quad * 8];
                s8b blo = *(const s8b*)&Hlo[(nt * 16 + c) * SS + ks * 32 + quad * 8];
                acc[0][ctn] = __builtin_amdgcn_mfma_f32_16x16x32_bf16(ah0, bhi, acc[0][ctn], 0, 0, 0);
                acc[0][ctn] = __builtin_amdgcn_mfma_f32_16x16x32_bf16(al0, bhi, acc[0][ctn], 0, 0, 0);
                acc[0][ctn] = __builtin_amdgcn_mfma_f32_16x16x32_bf16(ah0, blo, acc[0][ctn], 0, 0, 0);
                acc[1][ctn] = __builtin_amdgcn_mfma_f32_16x16x32_bf16(ah1, bhi, acc[1][ctn], 0, 0, 0);
                acc[1][ctn] = __builtin_amdgcn_mfma_f32_16x16x32_bf16(al1, bhi, acc[1][ctn], 0, 0, 0);
                acc[1][ctn] = __builtin_amdgcn_mfma_f32_16x16x32_bf16(ah1, blo, acc[1][ctn], 0, 0, 0);
            }
        }
    }

    // ---- phase 2: scatter z tile into LDS as split bf16 (A-operand layout) --
    __syncthreads();    // all waves done reading S/H (aliased by Z)
#pragma unroll
    for (int st = 0; st < 2; st++)
#pragma unroll
        for (int ctn = 0; ctn < NCW; ctn++)
#pragma unroll
            for (int r = 0; r < 4; r++) {
                const int row = 32 * rh + 16 * st + quad * 4 + r;
                const int col = (ch * NCW + ctn) * 16 + c;
                float v = acc[st][ctn][r];
                ushort hh = f2bf(v);
                Zhi[row * SZ2 + col] = (short)hh;
                Zlo[row * SZ2 + col] = (short)f2bf(v - bfbits2f(hh));
            }

    // ---- phase 3: h = relu(z @ Wd + bd), K = F, 128 output cols -----------
    const int rh2 = w >> 2;              // 32-row group (0..1)
    const int ch2 = w & 3;               // 32-col quarter (0..3)
    f4 acc2[2][2];
#pragma unroll
    for (int st = 0; st < 2; st++)
#pragma unroll
        for (int i = 0; i < 2; i++) acc2[st][i] = (f4){0.f, 0.f, 0.f, 0.f};

    constexpr int NKT = F / 32;
    for (int kt = 0; kt < NKT; kt++) {
        __syncthreads();
        {   // stage W tile: 128 cols x 32 k, hi+lo, one s8b pair per thread
            int cc = t >> 2, kk = (t & 3) * 8;
            size_t gsrc = (size_t)cc * F + kt * 32 + kk;
            *(s8b*)&Wsh[cc * 40 + kk] = *(const s8b*)&WT_hi[gsrc];
            *(s8b*)&Wsl[cc * 40 + kk] = *(const s8b*)&WT_lo[gsrc];
        }
        __syncthreads();

        s8b ah0 = *(const s8b*)&Zhi[(32 * rh2 + c) * SZ2 + kt * 32 + quad * 8];
        s8b al0 = *(const s8b*)&Zlo[(32 * rh2 + c) * SZ2 + kt * 32 + quad * 8];
        s8b ah1 = *(const s8b*)&Zhi[(32 * rh2 + 16 + c) * SZ2 + kt * 32 + quad * 8];
        s8b al1 = *(const s8b*)&Zlo[(32 * rh2 + 16 + c) * SZ2 + kt * 32 + quad * 8];
#pragma unroll
        for (int ct = 0; ct < 2; ct++) {
            s8b bh = *(const s8b*)&Wsh[(ch2 * 32 + ct * 16 + c) * 40 + quad * 8];
            s8b bl = *(const s8b*)&Wsl[(ch2 * 32 + ct * 16 + c) * 40 + quad * 8];
            acc2[0][ct] = __builtin_amdgcn_mfma_f32_16x16x32_bf16(ah0, bh, acc2[0][ct], 0, 0, 0);
            acc2[0][ct] = __builtin_amdgcn_mfma_f32_16x16x32_bf16(al0, bh, acc2[0][ct], 0, 0, 0);
            acc2[0][ct] = __builtin_amdgcn_mfma_f32_16x16x32_bf16(ah0, bl, acc2[0][ct], 0, 0, 0);
            acc2[1][ct] = __builtin_amdgcn_mfma_f32_16x16x32_bf16(ah1, bh, acc2[1][ct], 0, 0, 0);
            acc2[1][ct] = __builtin_amdgcn_mfma_f32_16x16x32_bf16(al1, bh, acc2[1][ct], 0, 0, 0);
            acc2[1][ct] = __builtin_amdgcn_mfma_f32_16x16x32_bf16(ah1, bl, acc2[1][ct], 0, 0, 0);
        }
    }

    // ---- epilogue: bias + relu, write h (+ split-transposed hT) -----------
#pragma unroll
    for (int st = 0; st < 2; st++) {
        const int rg0 = i0 + 32 * rh2 + 16 * st + quad * 4;
#pragma unroll
        for (int ct = 0; ct < 2; ct++) {
            const int col = ch2 * 32 + ct * 16 + c;
            float bv = bias[col];
            float vv[4];
#pragma unroll
            for (int r = 0; r < 4; r++) {
                float v = fmaxf(acc2[st][ct][r] + bv, 0.f);
                hout[((size_t)b * NN + rg0 + r) * 128 + col] = v;
                vv[r] = v;
            }
            if (WRITE_HT) {
                U4 ph, pl;
#pragma unroll
                for (int r = 0; r < 4; r++) {
                    ushort hh = f2bf(vv[r]);
                    ph.s[r] = (short)hh;
                    pl.s[r] = (short)f2bf(vv[r] - bfbits2f(hh));
                }
                size_t tb = ((size_t)b * 128 + col) * NN + rg0;
                *(s4b*)&hiT[tb] = ph.v;
                *(s4b*)&loT[tb] = pl.v;
            }
        }
    }
}

// ---------------------------------------------------------------------------
// MFMA dense GEMM, split-precision bf16, 32x(CB/2) wave tiles (R11).
// OMODE 0: fp32 out. 1: qkv bf16 (q,k row-major; V transposed) with paired
// 1D grid (col-block pairs 8 apart -> same XCD, adjacent in time).
// 3: fused out-proj + residual + final classifier.
// ---------------------------------------------------------------------------
template<int K1, int K2, int CB, bool RELU, bool RESID, int OMODE>
__global__ __launch_bounds__(256) void dense_mfma_kernel(
        const float* __restrict__ in1, const float* __restrict__ in2,
        const ushort* __restrict__ WT_hi, const ushort* __restrict__ WT_lo,
        const float* __restrict__ bias, const float* __restrict__ biask,
        const float* __restrict__ biasv,
        float* __restrict__ out, ushort* __restrict__ outq,
        const float* __restrict__ Wfin, const float* __restrict__ bfin,
        float* __restrict__ fout) {
    constexpr int KD  = K1 + K2;
    constexpr int NKT = KD / 32;
    constexpr int NCH = CB / 32;       // col-tiles per wave
    __shared__ short Xhi[64][40], Xlo[64][40];
    __shared__ short Whi[CB][40], Wlo[CB][40];
    __shared__ float red[64][2];       // OMODE3 cross-wave reduction

    int bx, by;
    if (OMODE == 1) {
        // pair (bx,0)/(bx,1) spaced 8 apart -> same XCD under round-robin
        const int xcd = blockIdx.x & 7, qq = blockIdx.x >> 3;
        by = qq & 1;
        bx = ((qq >> 1) << 3) | xcd;
    } else { bx = blockIdx.x; by = blockIdx.y; }
    const int r0 = bx * 64;
    const int c0 = by * CB;
    const int t  = threadIdx.x;
    const int w  = t >> 6, lane = t & 63;
    const int quad = lane >> 4, c = lane & 15;
    const int rh = w >> 1;             // 32-row group (0..1)
    const int ch = w & 1;              // col half (0..1)

    f4 acc[2][NCH];
#pragma unroll
    for (int st = 0; st < 2; st++)
#pragma unroll
        for (int i = 0; i < NCH; i++) acc[st][i] = (f4){0.f, 0.f, 0.f, 0.f};

    for (int kt = 0; kt < NKT; kt++) {
        const int k0 = kt * 32;
        __syncthreads();
        {
            int row = t >> 2, kk = (t & 3) * 8;
            int g = r0 + row;
            const float* p;
            if (K2 > 0) {
                int k = k0 + kk;
                p = (k < K1) ? (in1 + (size_t)g * K1 + k)
                             : (in2 + (size_t)g * K2 + (k - K1));
            } else {
                p = in1 + (size_t)g * K1 + k0 + kk;
            }
            float4 a = *(const float4*)p, bq = *(const float4*)(p + 4);
            float sv[8] = {a.x, a.y, a.z, a.w, bq.x, bq.y, bq.z, bq.w};
            U8 hi, lo;
#pragma unroll
            for (int i = 0; i < 8; i++) {
                ushort hh = f2bf(sv[i]);
                hi.s[i] = (short)hh;
                lo.s[i] = (short)f2bf(sv[i] - bfbits2f(hh));
            }
            *(s8b*)&Xhi[row][kk] = hi.v;
            *(s8b*)&Xlo[row][kk] = lo.v;
        }
        {
#pragma unroll
            for (int p = 0; p < CB / 64; p++) {
                int cc = p * 64 + (t >> 2), kk = (t & 3) * 8;
                size_t gsrc = (size_t)(c0 + cc) * KD + k0 + kk;
                *(s8b*)&Whi[cc][kk] = *(const s8b*)&WT_hi[gsrc];
                *(s8b*)&Wlo[cc][kk] = *(const s8b*)&WT_lo[gsrc];
            }
        }
        __syncthreads();

        s8b ah0 = *(const s8b*)&Xhi[32 * rh + c][quad * 8];
        s8b al0 = *(const s8b*)&Xlo[32 * rh + c][quad * 8];
        s8b ah1 = *(const s8b*)&Xhi[32 * rh + 16 + c][quad * 8];
        s8b al1 = *(const s8b*)&Xlo[32 * rh + 16 + c][quad * 8];
#pragma unroll
        for (int ct = 0; ct < NCH; ct++) {
            s8b bh = *(const s8b*)&Whi[ch * (CB / 2) + ct * 16 + c][quad * 8];
            s8b bl = *(const s8b*)&Wlo[ch * (CB / 2) + ct * 16 + c][quad * 8];
            acc[0][ct] = __builtin_amdgcn_mfma_f32_16x16x32_bf16(ah0, bh, acc[0][ct], 0, 0, 0);
            acc[0][ct] = __builtin_amdgcn_mfma_f32_16x16x32_bf16(al0, bh, acc[0][ct], 0, 0, 0);
            acc[0][ct] = __builtin_amdgcn_mfma_f32_16x16x32_bf16(ah0, bl, acc[0][ct], 0, 0, 0);
            acc[1][ct] = __builtin_amdgcn_mfma_f32_16x16x32_bf16(ah1, bh, acc[1][ct], 0, 0, 0);
            acc[1][ct] = __builtin_amdgcn_mfma_f32_16x16x32_bf16(al1, bh, acc[1][ct], 0, 0, 0);
            acc[1][ct] = __builtin_amdgcn_mfma_f32_16x16x32_bf16(ah1, bl, acc[1][ct], 0, 0, 0);
        }
    }

    if (OMODE == 3) {
        float fc[2][2][4];
#pragma unroll
        for (int st = 0; st < 2; st++)
#pragma unroll
            for (int o = 0; o < 2; o++)
#pragma unroll
                for (int r = 0; r < 4; r++) fc[st][o][r] = 0.f;
#pragma unroll
        for (int ct = 0; ct < NCH; ct++) {
            const int col = c0 + ch * (CB / 2) + ct * 16 + c;
            float bv = bias[col];
            float w0 = Wfin[col * 2], w1 = Wfin[col * 2 + 1];
#pragma unroll
            for (int st = 0; st < 2; st++) {
                const int rg = r0 + 32 * rh + 16 * st + quad * 4;
#pragma unroll
                for (int r = 0; r < 4; r++) {
                    float v = acc[st][ct][r] + bv;
                    if (RELU) v = fmaxf(v, 0.f);
                    if (RESID) v += out[(size_t)(rg + r) * 128 + col];
                    fc[st][0][r] += v * w0;
                    fc[st][1][r] += v * w1;
                }
            }
        }
#pragma unroll
        for (int st = 0; st < 2; st++)
#pragma unroll
            for (int r = 0; r < 4; r++) {
                float a0 = fc[st][0][r], a1 = fc[st][1][r];
#pragma unroll
                for (int off = 1; off < 16; off <<= 1) {
                    a0 += __shfl_xor(a0, off, 16);
                    a1 += __shfl_xor(a1, off, 16);
                }
                fc[st][0][r] = a0; fc[st][1][r] = a1;
            }
        if (ch == 1 && c == 0) {
#pragma unroll
            for (int st = 0; st < 2; st++)
#pragma unroll
                for (int r = 0; r < 4; r++) {
                    int lr = 32 * rh + 16 * st + quad * 4 + r;
                    red[lr][0] = fc[st][0][r];
                    red[lr][1] = fc[st][1][r];
                }
        }
        __syncthreads();
        if (ch == 0 && c == 0) {
#pragma unroll
            for (int st = 0; st < 2; st++)
#pragma unroll
                for (int r = 0; r < 4; r++) {
                    int lr = 32 * rh + 16 * st + quad * 4 + r;
                    size_t row = (size_t)r0 + lr;
                    fout[row * 2]     = fc[st][0][r] + red[lr][0] + bfin[0];
                    fout[row * 2 + 1] = fc[st][1][r] + red[lr][1] + bfin[1];
                }
        }
        return;
    }
#pragma unroll
    for (int st = 0; st < 2; st++) {
        const int row_g0 = r0 + 32 * rh + 16 * st + quad * 4;
#pragma unroll
        for (int ct = 0; ct < NCH; ct++) {
            const int col = c0 + ch * (CB / 2) + ct * 16 + c;
            if (OMODE == 1) {
                int tensor = col >> 7, cc2 = col & 127;
                float bv = (tensor == 0 ? bias : tensor == 1 ? biask : biasv)[cc2];
                int head = cc2 >> 6, d = cc2 & 63;
                int b = row_g0 >> 10, n = row_g0 & 1023;
                if (tensor == 2) {
                    // V^T [B,H,64,N]: 4 consecutive n -> one 8B packed store
                    U4 pk;
#pragma unroll
                    for (int r = 0; r < 4; r++) pk.s[r] = (short)f2bf(acc[st][ct][r] + bv);
                    size_t addr = (((size_t)b * HEADS + head) * 64 + d) * NN + n;
                    *(s4b*)&outq[2 * SZQ + addr] = pk.v;
                } else {
                    ushort* dst = outq + (size_t)tensor * SZQ
                                + (((size_t)b * HEADS + head) * NN + n) * 64 + d;
#pragma unroll
                    for (int r = 0; r < 4; r++) dst[(size_t)r * 64] = f2bf(acc[st][ct][r] + bv);
                }
            } else {
                float bv = bias[col];
#pragma unroll
                for (int r = 0; r < 4; r++) {
                    float v = acc[st][ct][r] + bv;
                    if (RELU) v = fmaxf(v, 0.f);
                    size_t o = (size_t)(row_g0 + r) * 128 + col;
                    if (RESID) v += out[o];
                    out[o] = v;
                }
            }
        }
    }
}

// ---------------------------------------------------------------------------
// MFMA flash attention v4 + XCD swizzle: the 16 blocks sharing one
// (b,h) K/V panel (256KB) land on the same XCD's L2.
// ---------------------------------------------------------------------------
__global__ __launch_bounds__(256) void attn_mfma_kernel(const ushort* __restrict__ q,
                                                        const ushort* __restrict__ k,
                                                        const ushort* __restrict__ vt,
                                                        float* __restrict__ ctx) {
    __shared__ short Ks[128][72];
    __shared__ short Vt[64][136];

    // bijective XCD swizzle: 1024 blocks = 8 xcd * 8 bh-per-xcd * 16 n0
    const int bidx = blockIdx.x;
    const int u  = bidx >> 3;
    const int bh = (bidx & 7) + 8 * (u >> 4);
    const int n0 = (u & 15) * 64;
    const int b  = bh >> 1, h = bh & 1;
    const int t  = threadIdx.x;
    const int w  = t >> 6;
    const int lane = t & 63;
    const int quad = lane >> 4, c = lane & 15;
    const size_t kvbase = (size_t)bh * NN * 64;   // same elem count for k and vt
    const float scale = 0.125f;

    s8b qf0, qf1;
    {
        const ushort* qrow = q + kvbase + (size_t)(n0 + 16 * w + c) * 64;
        qf0 = *(const s8b*)(qrow + quad * 8);
        qf1 = *(const s8b*)(qrow + 32 + quad * 8);
    }

    f4 O[4];
#pragma unroll
    for (int i = 0; i < 4; i++) O[i] = (f4){0.f, 0.f, 0.f, 0.f};
    float l_i = 0.f;

    for (int kt0 = 0; kt0 < NN; kt0 += 128) {
        __syncthreads();
        {   // K: 128 keys row-major, 4 b128 per thread
            int key = t >> 2, d0 = (t & 3) * 16;
#pragma unroll
            for (int half = 0; half < 2; half++) {
                const ushort* kr = k + kvbase + (size_t)(kt0 + 64 * half + key) * 64 + d0;
                *(s8b*)&Ks[64 * half + key][d0]     = *(const s8b*)kr;
                *(s8b*)&Ks[64 * half + key][d0 + 8] = *(const s8b*)(kr + 8);
            }
            // V^T: row d = t>>2, cols (t&3)*32..+31, 4 b128 copies
            int d = t >> 2, ch = (t & 3) * 32;
            const ushort* vr = vt + kvbase + (size_t)d * NN + kt0 + ch;
            *(s8b*)&Vt[d][ch]      = *(const s8b*)vr;
            *(s8b*)&Vt[d][ch + 8]  = *(const s8b*)(vr + 8);
            *(s8b*)&Vt[d][ch + 16] = *(const s8b*)(vr + 16);
            *(s8b*)&Vt[d][ch + 24] = *(const s8b*)(vr + 24);
        }
        __syncthreads();

        // ---- S for 4 groups of 32 keys ----
        f4 sg[4][2];
#pragma unroll
        for (int g = 0; g < 4; g++) {
            const int kb = g * 32;
            sg[g][0] = (f4){0.f, 0.f, 0.f, 0.f};
            sg[g][1] = (f4){0.f, 0.f, 0.f, 0.f};
#pragma unroll
            for (int ch = 0; ch < 2; ch++) {
                s8b ka = *(const s8b*)&Ks[kb + c][ch * 32 + quad * 8];
                s8b kB = *(const s8b*)&Ks[kb + 16 + c][ch * 32 + quad * 8];
                s8b qf = ch ? qf1 : qf0;
                sg[g][0] = __builtin_amdgcn_mfma_f32_16x16x32_bf16(ka, qf, sg[g][0], 0, 0, 0);
                sg[g][1] = __builtin_amdgcn_mfma_f32_16x16x32_bf16(kB, qf, sg[g][1], 0, 0, 0);
            }
        }
        // ---- softmax numerator without running max ----
        float pv[4][8];
        float ps = 0.f;
#pragma unroll
        for (int g = 0; g < 4; g++)
#pragma unroll
            for (int r = 0; r < 4; r++) {
                pv[g][r]     = __expf(sg[g][0][r] * scale);
                pv[g][4 + r] = __expf(sg[g][1][r] * scale);
                ps += pv[g][r] + pv[g][4 + r];
            }
        ps += __shfl_xor(ps, 16);
        ps += __shfl_xor(ps, 32);
        l_i += ps;

        // ---- P transpose + PV per group ----
        int addr0 = ((((2 * quad) & 3) << 4) | c) << 2;
        int addr1 = ((((2 * quad + 1) & 3) << 4) | c) << 2;
        int tsel = quad >> 1;
#pragma unroll
        for (int g = 0; g < 4; g++) {
            const int kb = g * 32;
            uint Da01 = pk_bf16(pv[g][0], pv[g][1]), Da23 = pk_bf16(pv[g][2], pv[g][3]);
            uint Db01 = pk_bf16(pv[g][4], pv[g][5]), Db23 = pk_bf16(pv[g][6], pv[g][7]);
            int A01_0 = __builtin_amdgcn_ds_bpermute(addr0, (int)Da01);
            int A23_0 = __builtin_amdgcn_ds_bpermute(addr0, (int)Da23);
            int B01_0 = __builtin_amdgcn_ds_bpermute(addr0, (int)Db01);
            int B23_0 = __builtin_amdgcn_ds_bpermute(addr0, (int)Db23);
            int A01_1 = __builtin_amdgcn_ds_bpermute(addr1, (int)Da01);
            int A23_1 = __builtin_amdgcn_ds_bpermute(addr1, (int)Da23);
            int B01_1 = __builtin_amdgcn_ds_bpermute(addr1, (int)Db01);
            int B23_1 = __builtin_amdgcn_ds_bpermute(addr1, (int)Db23);
            union { int i[4]; s8b s; } pf;
            pf.i[0] = tsel ? B01_0 : A01_0;
            pf.i[1] = tsel ? B23_0 : A23_0;
            pf.i[2] = tsel ? B01_1 : A01_1;
            pf.i[3] = tsel ? B23_1 : A23_1;
#pragma unroll
            for (int dt = 0; dt < 4; dt++) {
                s8b vf = *(const s8b*)&Vt[16 * dt + c][kb + quad * 8];
                O[dt] = __builtin_amdgcn_mfma_f32_16x16x32_bf16(vf, pf.s, O[dt], 0, 0, 0);
            }
        }
    }

    float inv = 1.0f / l_i;
    float* crow = ctx + ((size_t)b * NN + n0 + 16 * w + c) * HIDD + h * DH;
#pragma unroll
    for (int dt = 0; dt < 4; dt++)
#pragma unroll
        for (int r = 0; r < 4; r++)
            crow[16 * dt + 4 * quad + r] = O[dt][r] * inv;
}

// ---------------------------------------------------------------------------
extern "C" void kernel_launch(void* const* d_in, const int* in_sizes, int n_in,
                              void* d_out, int out_size, void* d_ws, size_t ws_size,
                              hipStream_t stream) {
    (void)in_sizes; (void)n_in; (void)out_size; (void)ws_size;
    const float* X     = (const float*)d_in[0];
    const float* A     = (const float*)d_in[1];
    const float* T     = (const float*)d_in[2];
    const float* theta = (const float*)d_in[3];
    const float* W_raw = (const float*)d_in[4];
    const float* b_raw = (const float*)d_in[5];
    const float* Wd0   = (const float*)d_in[6];
    const float* bd0   = (const float*)d_in[7];
    const float* Wd1   = (const float*)d_in[8];
    const float* bd1   = (const float*)d_in[9];
    const float* W_fin = (const float*)d_in[10];
    const float* b_fin = (const float*)d_in[11];
    const float* Wq0 = (const float*)d_in[12]; const float* bq0 = (const float*)d_in[13];
    const float* Wk0 = (const float*)d_in[14]; const float* bk0 = (const float*)d_in[15];
    const float* Wv0 = (const float*)d_in[16]; const float* bv0 = (const float*)d_in[17];
    const float* Wo0 = (const float*)d_in[18]; const float* bo0 = (const float*)d_in[19];
    const float* Wq1 = (const float*)d_in[20]; const float* bq1 = (const float*)d_in[21];
    const float* Wk1 = (const float*)d_in[22]; const float* bk1 = (const float*)d_in[23];
    const float* Wv1 = (const float*)d_in[24]; const float* bv1 = (const float*)d_in[25];
    const float* Wo1 = (const float*)d_in[26]; const float* bo1 = (const float*)d_in[27];

    float* ws   = (float*)d_ws;
    const size_t SZ = (size_t)BB * NN * HIDD;
    ushort* Q0hi = (ushort*)ws;
    ushort* Q0lo = Q0hi + (size_t)NN * NN;
    float* hp   = ws + (size_t)NN * NN;
    float* h    = hp + SZ;
    float* z    = h + SZ;
    ushort* qb  = (ushort*)(z + SZ);          // q | k | v^T contiguous (3*SZ)
    ushort* kb  = qb + SZ;
    ushort* XT_hi = qb + 3 * SZ;
    ushort* XT_lo = XT_hi + SZ / 2;
    ushort* hT_hi = XT_lo + SZ / 2;
    ushort* hT_lo = hT_hi + SZ;
    ushort* WT_hi = hT_lo + SZ;
    ushort* WT_lo = WT_hi + 262144;
    ushort* Q1hi = WT_lo + 262144;
    ushort* Q1lo = Q1hi + (size_t)NN * NN;

    const int OFF_RAW = 0, OFF_D0 = 8192, OFF_D1 = 16384, OFF_QKV0 = 32768,
              OFF_O0 = 131072, OFF_QKV1 = 147456, OFF_O1 = 245760;

    const int attnGrid = BB * HEADS * (NN / 64);
    const int diffGrid = BB * (NN / 64);
    const dim3 dg1(512, 1);

    // fused prep_w + X transpose/split + build_q layers 0 AND 1
    setup_kernel<<<2560, 256, 0, stream>>>(W_raw, Wd0, Wd1, Wq0, Wk0, Wv0, Wo0,
                                           Wq1, Wk1, Wv1, Wo1, WT_hi, WT_lo,
                                           T, theta, Q0hi, Q0lo, Q1hi, Q1lo,
                                           X, XT_hi, XT_lo);

    // ---- layer 0 ----
    dense_mfma_kernel<64, 0, 128, false, false, 0><<<dg1, 256, 0, stream>>>(
        X, nullptr, WT_hi + OFF_RAW, WT_lo + OFF_RAW, b_raw, nullptr, nullptr,
        hp, nullptr, nullptr, nullptr, nullptr);
    diff_dense_kernel<64, true><<<diffGrid, 512, 0, stream>>>(
        Q0hi, Q0lo, A, XT_hi, XT_lo, WT_hi + OFF_D0, WT_lo + OFF_D0, bd0,
        h, hT_hi, hT_lo);
    dense_mfma_kernel<128, 128, 192, false, false, 1><<<1024, 256, 0, stream>>>(
        h, hp, WT_hi + OFF_QKV0, WT_lo + OFF_QKV0, bq0, bk0, bv0,
        nullptr, qb, nullptr, nullptr, nullptr);
    attn_mfma_kernel<<<attnGrid, 256, 0, stream>>>(qb, kb, qb + 2 * SZ, z);
    dense_mfma_kernel<128, 0, 128, true, false, 0><<<dg1, 256, 0, stream>>>(
        z, nullptr, WT_hi + OFF_O0, WT_lo + OFF_O0, bo0, nullptr, nullptr,
        hp, nullptr, nullptr, nullptr, nullptr);

    // ---- layer 1 ----
    diff_dense_kernel<128, false><<<diffGrid, 512, 0, stream>>>(
        Q1hi, Q1lo, A, hT_hi, hT_lo, WT_hi + OFF_D1, WT_lo + OFF_D1, bd1,
        h, nullptr, nullptr);
    dense_mfma_kernel<128, 128, 192, false, false, 1><<<1024, 256, 0, stream>>>(
        h, hp, WT_hi + OFF_QKV1, WT_lo + OFF_QKV1, bq1, bk1, bv1,
        nullptr, qb, nullptr, nullptr, nullptr);
    attn_mfma_kernel<<<attnGrid, 256, 0, stream>>>(qb, kb, qb + 2 * SZ, z);
    dense_mfma_kernel<128, 0, 128, true, true, 3><<<dg1, 256, 0, stream>>>(
        z, nullptr, WT_hi + OFF_O1, WT_lo + OFF_O1, bo1, nullptr, nullptr,
        hp, nullptr, W_fin, b_fin, (float*)d_out);
}

// Round 3
// 484.217 us; speedup vs baseline: 1.0874x; 1.0441x over previous
//
#include <hip/hip_runtime.h>
#include <hip/hip_bf16.h>

typedef __hip_bfloat16 bf16;
typedef __attribute__((ext_vector_type(8))) short s8b;   // 8 bf16 (4 VGPRs)
typedef __attribute__((ext_vector_type(4))) short s4b;   // 4 bf16 (8B)
typedef __attribute__((ext_vector_type(4))) float f4;    // MFMA acc

#define BB   32
#define NN   1024
#define FIN  64
#define HEADS 2
#define DH   64
#define HIDD 128
#define SZQ  ((size_t)BB * NN * HIDD)

__device__ __forceinline__ ushort f2bf(float x) {
    bf16 h = __float2bfloat16(x);
    return *(ushort*)&h;
}
__device__ __forceinline__ float bfbits2f(ushort h) {
    union { uint u; float f; } c; c.u = (uint)h << 16; return c.f;
}
__device__ __forceinline__ uint pk_bf16(float lo, float hi) {
    return (uint)f2bf(lo) | ((uint)f2bf(hi) << 16);
}
union U8 { short s[8]; s8b v; };
union U4 { short s[4]; s4b v; };
union UQ { ushort u[8]; s8b v; };

// ---------------------------------------------------------------------------
// Fused setup: [0,1024) prep_w | [1024,1536) transpose/split X |
// [1536,2048) build_q layer 0 | [2048,2560) build_q layer 1.
// ---------------------------------------------------------------------------
__global__ __launch_bounds__(256) void setup_kernel(
        const float* __restrict__ raw, const float* __restrict__ d0,
        const float* __restrict__ d1,
        const float* __restrict__ q0w, const float* __restrict__ k0w,
        const float* __restrict__ v0w, const float* __restrict__ o0w,
        const float* __restrict__ q1w, const float* __restrict__ k1w,
        const float* __restrict__ v1w, const float* __restrict__ o1w,
        ushort* __restrict__ Whi, ushort* __restrict__ Wlo,
        const float* __restrict__ T, const float* __restrict__ theta,
        ushort* __restrict__ Q0hi, ushort* __restrict__ Q0lo,
        ushort* __restrict__ Q1hi, ushort* __restrict__ Q1lo,
        const float* __restrict__ X,
        ushort* __restrict__ XT_hi, ushort* __restrict__ XT_lo) {
    __shared__ float tile[64][65];
    const int bid = blockIdx.x;
    const int t = threadIdx.x;
    if (bid < 1024) {
        int id = bid * 256 + t;
        const float* src; int K, off;
        if      (id <   8192) { src = raw; K =  64; off = 0; }
        else if (id <  16384) { src = d0;  K =  64; off = 8192; }
        else if (id <  32768) { src = d1;  K = 128; off = 16384; }
        else if (id <  65536) { src = q0w; K = 256; off = 32768; }
        else if (id <  98304) { src = k0w; K = 256; off = 65536; }
        else if (id < 131072) { src = v0w; K = 256; off = 98304; }
        else if (id < 147456) { src = o0w; K = 128; off = 131072; }
        else if (id < 180224) { src = q1w; K = 256; off = 147456; }
        else if (id < 212992) { src = k1w; K = 256; off = 180224; }
        else if (id < 245760) { src = v1w; K = 256; off = 212992; }
        else                  { src = o1w; K = 128; off = 245760; }
        int il = id - off;
        int k = il >> 7, c = il & 127;
        float w = src[il];
        ushort h = f2bf(w);
        Whi[off + c * K + k] = h;
        Wlo[off + c * K + k] = f2bf(w - bfbits2f(h));
    } else if (bid < 1536) {
        const int tb = bid - 1024;
        const int b  = tb >> 4;
        const int n0 = (tb & 15) * 64;
        {
            int nl = t >> 2, f0 = (t & 3) * 16;
            const float* xp = X + ((size_t)b * NN + n0 + nl) * 64 + f0;
#pragma unroll
            for (int i = 0; i < 16; i += 4)
                *(float4*)&tile[nl][f0 + i] = *(const float4*)(xp + i);
        }
        __syncthreads();
        {
            int f = t >> 2, n1 = (t & 3) * 16;
            U8 h0, h1, l0, l1;
#pragma unroll
            for (int i = 0; i < 16; i++) {
                float v = tile[n1 + i][f];
                ushort hh = f2bf(v);
                ushort ll = f2bf(v - bfbits2f(hh));
                if (i < 8) { h0.s[i] = (short)hh; l0.s[i] = (short)ll; }
                else       { h1.s[i - 8] = (short)hh; l1.s[i - 8] = (short)ll; }
            }
            size_t gb = ((size_t)b * 64 + f) * NN + n0 + n1;
            *(s8b*)&XT_hi[gb]     = h0.v;  *(s8b*)&XT_hi[gb + 8] = h1.v;
            *(s8b*)&XT_lo[gb]     = l0.v;  *(s8b*)&XT_lo[gb + 8] = l1.v;
        }
    } else {
        const int layer = (bid < 2048) ? 0 : 1;
        ushort* Qhi = layer ? Q1hi : Q0hi;
        ushort* Qlo = layer ? Q1lo : Q0lo;
        float t0 = theta[layer * 3 + 0];
        float t1 = theta[layer * 3 + 1];
        float t2 = theta[layer * 3 + 2];
        float m  = fmaxf(t0, fmaxf(t1, t2));
        float e0 = expf(t0 - m), e1 = expf(t1 - m), e2 = expf(t2 - m);
        float inv = 1.0f / (e0 + e1 + e2);
        e0 *= inv; e1 *= inv; e2 *= inv;
        size_t base = ((size_t)((bid - 1536) & 511) * 256 + t) * 8;
        const float* Tl = T + (size_t)layer * 3 * NN * NN;
        U8 hi, lo;
#pragma unroll
        for (int i = 0; i < 8; i++) {
            float q = e0 * Tl[base + i]
                    + e1 * Tl[base + i + (size_t)NN * NN]
                    + e2 * Tl[base + i + (size_t)2 * NN * NN];
            ushort hh = f2bf(q);
            hi.s[i] = (short)hh;
            lo.s[i] = (short)f2bf(q - bfbits2f(hh));
        }
        *(s8b*)&Qhi[base] = hi.v;
        *(s8b*)&Qlo[base] = lo.v;
    }
}

// ---------------------------------------------------------------------------
// R12 fused diffusion + post-dense (unchanged in R13):
//   z[b,i,f] = sum_j (Q[i,j]*A[b,i,j]) * h[b,j,f]   (phase 1, in-register)
//   h_out    = relu(z @ Wd + bd)                    (phase 3, z via LDS only)
// ---------------------------------------------------------------------------
template<int F, bool WRITE_HT>
__global__ __launch_bounds__(512, 4) void diff_dense_kernel(
        const ushort* __restrict__ Qhi, const ushort* __restrict__ Qlo,
        const float* __restrict__ A,
        const ushort* __restrict__ hT_hi, const ushort* __restrict__ hT_lo,
        const ushort* __restrict__ WT_hi, const ushort* __restrict__ WT_lo,
        const float* __restrict__ bias,
        float* __restrict__ hout,
        ushort* __restrict__ hiT, ushort* __restrict__ loT) {
    constexpr int SS  = 72;
    constexpr int NT  = F / 16;
    constexpr int NCW = NT / 4;          // col-tiles per wave in phase 1
    constexpr int SZ2 = F + 8;           // Z LDS stride (shorts)
    constexpr int P1 = 2 * 64 * SS + 2 * F * SS;
    constexpr int P2 = 2 * 64 * SZ2 + 2 * 128 * 40;
    __shared__ short smem[(P1 > P2) ? P1 : P2];
    short* Shi = smem;                   // [64][SS]
    short* Slo = Shi + 64 * SS;
    short* Hhi = Slo + 64 * SS;          // [F][SS]
    short* Hlo = Hhi + (size_t)F * SS;
    short* Zhi = smem;                   // [64][SZ2]  (aliases S/H after phase 1)
    short* Zlo = Zhi + 64 * SZ2;
    short* Wsh = Zlo + 64 * SZ2;         // [128][40]
    short* Wsl = Wsh + 128 * 40;

    // bijective XCD swizzle: 512 blocks = 8 xcd * 4 b-per-xcd * 16 i0
    const int bidx = blockIdx.x;
    const int u  = bidx >> 3;
    const int b  = (bidx & 7) + 8 * (u >> 4);
    const int i0 = (u & 15) * 64;
    const int t  = threadIdx.x;
    const int w  = t >> 6, lane = t & 63;
    const int quad = lane >> 4, c = lane & 15;
    const int rh = w >> 2;               // 32-row group (0..1)
    const int ch = w & 3;                // col quarter (0..3)

    const int srow = t >> 3, scol = (t & 7) * 8;
    const float*  Ap = A   + ((size_t)b * NN + i0 + srow) * NN + scol;
    const ushort* Qh = Qhi + (size_t)(i0 + srow) * NN + scol;
    const ushort* Ql = Qlo + (size_t)(i0 + srow) * NN + scol;
    constexpr int HTR = 512 / F;
    constexpr int HJ  = 64 / HTR;
    constexpr int HV  = HJ / 8;
    const int hrow = t / HTR, hcol = (t % HTR) * HJ;
    const ushort* Hh = hT_hi + ((size_t)b * F + hrow) * NN + hcol;
    const ushort* Hl = hT_lo + ((size_t)b * F + hrow) * NN + hcol;

    f4 acc[2][NCW];
#pragma unroll
    for (int st = 0; st < 2; st++)
#pragma unroll
        for (int i = 0; i < NCW; i++) acc[st][i] = (f4){0.f, 0.f, 0.f, 0.f};

    float4 a0 = *(const float4*)Ap, a1 = *(const float4*)(Ap + 4);
    s8b hhv[HV], hlv[HV];
#pragma unroll
    for (int vv = 0; vv < HV; vv++) {
        hhv[vv] = *(const s8b*)(Hh + 8 * vv);
        hlv[vv] = *(const s8b*)(Hl + 8 * vv);
    }

#pragma unroll 1
    for (int j0 = 0; j0 < NN; j0 += 64) {
        UQ qh, ql;
        qh.v = *(const s8b*)(Qh + j0);
        ql.v = *(const s8b*)(Ql + j0);
        __syncthreads();
        {
            float av[8] = {a0.x, a0.y, a0.z, a0.w, a1.x, a1.y, a1.z, a1.w};
            U8 hi, lo;
#pragma unroll
            for (int i = 0; i < 8; i++) {
                float q = bfbits2f(qh.u[i]) + bfbits2f(ql.u[i]);
                float s = q * av[i];
                ushort hb = f2bf(s);
                hi.s[i] = (short)hb;
                lo.s[i] = (short)f2bf(s - bfbits2f(hb));
            }
            *(s8b*)&Shi[srow * SS + scol] = hi.v;
            *(s8b*)&Slo[srow * SS + scol] = lo.v;
#pragma unroll
            for (int vv = 0; vv < HV; vv++) {
                *(s8b*)&Hhi[hrow * SS + hcol + 8 * vv] = hhv[vv];
                *(s8b*)&Hlo[hrow * SS + hcol + 8 * vv] = hlv[vv];
            }
        }
        if (j0 + 64 < NN) {
            a0 = *(const float4*)(Ap + j0 + 64);
            a1 = *(const float4*)(Ap + j0 + 68);
#pragma unroll
            for (int vv = 0; vv < HV; vv++) {
                hhv[vv] = *(const s8b*)(Hh + j0 + 64 + 8 * vv);
                hlv[vv] = *(const s8b*)(Hl + j0 + 64 + 8 * vv);
            }
        }
        __syncthreads();

#pragma unroll
        for (int ks = 0; ks < 2; ks++) {
            s8b ah0 = *(const s8b*)&Shi[(32 * rh + c) * SS + ks * 32 + quad * 8];
            s8b al0 = *(const s8b*)&Slo[(32 * rh + c) * SS + ks * 32 + quad * 8];
            s8b ah1 = *(const s8b*)&Shi[(32 * rh + 16 + c) * SS + ks * 32 + quad * 8];
            s8b al1 = *(const s8b*)&Slo[(32 * rh + 16 + c) * SS + ks * 32 + quad * 8];
#pragma unroll
            for (int ctn = 0; ctn < NCW; ctn++) {
                const int nt = ch * NCW + ctn;
                s8b bhi = *(const s8b*)&Hhi[(nt * 16 + c) * SS + ks * 32 + quad * 8];
                s8b blo = *(const s8b*)&Hlo[(nt * 16 + c) * SS + ks * 32 + quad * 8];
                acc[0][ctn] = __builtin_amdgcn_mfma_f32_16x16x32_bf16(ah0, bhi, acc[0][ctn], 0, 0, 0);
                acc[0][ctn] = __builtin_amdgcn_mfma_f32_16x16x32_bf16(al0, bhi, acc[0][ctn], 0, 0, 0);
                acc[0][ctn] = __builtin_amdgcn_mfma_f32_16x16x32_bf16(ah0, blo, acc[0][ctn], 0, 0, 0);
                acc[1][ctn] = __builtin_amdgcn_mfma_f32_16x16x32_bf16(ah1, bhi, acc[1][ctn], 0, 0, 0);
                acc[1][ctn] = __builtin_amdgcn_mfma_f32_16x16x32_bf16(al1, bhi, acc[1][ctn], 0, 0, 0);
                acc[1][ctn] = __builtin_amdgcn_mfma_f32_16x16x32_bf16(ah1, blo, acc[1][ctn], 0, 0, 0);
            }
        }
    }

    // ---- phase 2: scatter z tile into LDS as split bf16 (A-operand layout) --
    __syncthreads();    // all waves done reading S/H (aliased by Z)
#pragma unroll
    for (int st = 0; st < 2; st++)
#pragma unroll
        for (int ctn = 0; ctn < NCW; ctn++)
#pragma unroll
            for (int r = 0; r < 4; r++) {
                const int row = 32 * rh + 16 * st + quad * 4 + r;
                const int col = (ch * NCW + ctn) * 16 + c;
                float v = acc[st][ctn][r];
                ushort hh = f2bf(v);
                Zhi[row * SZ2 + col] = (short)hh;
                Zlo[row * SZ2 + col] = (short)f2bf(v - bfbits2f(hh));
            }

    // ---- phase 3: h = relu(z @ Wd + bd), K = F, 128 output cols -----------
    const int rh2 = w >> 2;              // 32-row group (0..1)
    const int ch2 = w & 3;               // 32-col quarter (0..3)
    f4 acc2[2][2];
#pragma unroll
    for (int st = 0; st < 2; st++)
#pragma unroll
        for (int i = 0; i < 2; i++) acc2[st][i] = (f4){0.f, 0.f, 0.f, 0.f};

    constexpr int NKT = F / 32;
    for (int kt = 0; kt < NKT; kt++) {
        __syncthreads();
        {   // stage W tile: 128 cols x 32 k, hi+lo, one s8b pair per thread
            int cc = t >> 2, kk = (t & 3) * 8;
            size_t gsrc = (size_t)cc * F + kt * 32 + kk;
            *(s8b*)&Wsh[cc * 40 + kk] = *(const s8b*)&WT_hi[gsrc];
            *(s8b*)&Wsl[cc * 40 + kk] = *(const s8b*)&WT_lo[gsrc];
        }
        __syncthreads();

        s8b ah0 = *(const s8b*)&Zhi[(32 * rh2 + c) * SZ2 + kt * 32 + quad * 8];
        s8b al0 = *(const s8b*)&Zlo[(32 * rh2 + c) * SZ2 + kt * 32 + quad * 8];
        s8b ah1 = *(const s8b*)&Zhi[(32 * rh2 + 16 + c) * SZ2 + kt * 32 + quad * 8];
        s8b al1 = *(const s8b*)&Zlo[(32 * rh2 + 16 + c) * SZ2 + kt * 32 + quad * 8];
#pragma unroll
        for (int ct = 0; ct < 2; ct++) {
            s8b bh = *(const s8b*)&Wsh[(ch2 * 32 + ct * 16 + c) * 40 + quad * 8];
            s8b bl = *(const s8b*)&Wsl[(ch2 * 32 + ct * 16 + c) * 40 + quad * 8];
            acc2[0][ct] = __builtin_amdgcn_mfma_f32_16x16x32_bf16(ah0, bh, acc2[0][ct], 0, 0, 0);
            acc2[0][ct] = __builtin_amdgcn_mfma_f32_16x16x32_bf16(al0, bh, acc2[0][ct], 0, 0, 0);
            acc2[0][ct] = __builtin_amdgcn_mfma_f32_16x16x32_bf16(ah0, bl, acc2[0][ct], 0, 0, 0);
            acc2[1][ct] = __builtin_amdgcn_mfma_f32_16x16x32_bf16(ah1, bh, acc2[1][ct], 0, 0, 0);
            acc2[1][ct] = __builtin_amdgcn_mfma_f32_16x16x32_bf16(al1, bh, acc2[1][ct], 0, 0, 0);
            acc2[1][ct] = __builtin_amdgcn_mfma_f32_16x16x32_bf16(ah1, bl, acc2[1][ct], 0, 0, 0);
        }
    }

    // ---- epilogue: bias + relu, write h (+ split-transposed hT) -----------
#pragma unroll
    for (int st = 0; st < 2; st++) {
        const int rg0 = i0 + 32 * rh2 + 16 * st + quad * 4;
#pragma unroll
        for (int ct = 0; ct < 2; ct++) {
            const int col = ch2 * 32 + ct * 16 + c;
            float bv = bias[col];
            float vv[4];
#pragma unroll
            for (int r = 0; r < 4; r++) {
                float v = fmaxf(acc2[st][ct][r] + bv, 0.f);
                hout[((size_t)b * NN + rg0 + r) * 128 + col] = v;
                vv[r] = v;
            }
            if (WRITE_HT) {
                U4 ph, pl;
#pragma unroll
                for (int r = 0; r < 4; r++) {
                    ushort hh = f2bf(vv[r]);
                    ph.s[r] = (short)hh;
                    pl.s[r] = (short)f2bf(vv[r] - bfbits2f(hh));
                }
                size_t tb = ((size_t)b * 128 + col) * NN + rg0;
                *(s4b*)&hiT[tb] = ph.v;
                *(s4b*)&loT[tb] = pl.v;
            }
        }
    }
}

// ---------------------------------------------------------------------------
// R13: MFMA dense GEMM, split-precision bf16, 128-ROW blocks (8 waves, 512
// threads). W/X staging + barriers amortized over 2x rows vs R12. Wave grid
// 4 rh x 2 ch; per-output accumulation order unchanged -> bit-identical.
// OMODE 0: fp32 out. 1: qkv bf16 (paired 1D grid for XCD L2 reuse).
// 3: fused out-proj + residual + final classifier.
// ---------------------------------------------------------------------------
template<int K1, int K2, int CB, bool RELU, bool RESID, int OMODE>
__global__ __launch_bounds__(512) void dense_mfma_kernel(
        const float* __restrict__ in1, const float* __restrict__ in2,
        const ushort* __restrict__ WT_hi, const ushort* __restrict__ WT_lo,
        const float* __restrict__ bias, const float* __restrict__ biask,
        const float* __restrict__ biasv,
        float* __restrict__ out, ushort* __restrict__ outq,
        const float* __restrict__ Wfin, const float* __restrict__ bfin,
        float* __restrict__ fout) {
    constexpr int KD  = K1 + K2;
    constexpr int NKT = KD / 32;
    constexpr int NCH = CB / 32;       // col-tiles per wave (ch covers CB/2)
    __shared__ short Xhi[128][40], Xlo[128][40];
    __shared__ short Whi[CB][40], Wlo[CB][40];
    __shared__ float red[128][2];      // OMODE3 cross-wave reduction

    int bx, by;
    if (OMODE == 1) {
        // pair (bx,0)/(bx,1) spaced 8 apart -> same XCD under round-robin
        const int xcd = blockIdx.x & 7, qq = blockIdx.x >> 3;
        by = qq & 1;
        bx = ((qq >> 1) << 3) | xcd;
    } else { bx = blockIdx.x; by = blockIdx.y; }
    const int r0 = bx * 128;
    const int c0 = by * CB;
    const int t  = threadIdx.x;
    const int w  = t >> 6, lane = t & 63;
    const int quad = lane >> 4, c = lane & 15;
    const int rh = w >> 1;             // 32-row group (0..3)
    const int ch = w & 1;              // col half (0..1)

    f4 acc[2][NCH];
#pragma unroll
    for (int st = 0; st < 2; st++)
#pragma unroll
        for (int i = 0; i < NCH; i++) acc[st][i] = (f4){0.f, 0.f, 0.f, 0.f};

    for (int kt = 0; kt < NKT; kt++) {
        const int k0 = kt * 32;
        __syncthreads();
        {
            int row = t >> 2, kk = (t & 3) * 8;   // 512 thr cover 128 rows
            int g = r0 + row;
            const float* p;
            if (K2 > 0) {
                int k = k0 + kk;
                p = (k < K1) ? (in1 + (size_t)g * K1 + k)
                             : (in2 + (size_t)g * K2 + (k - K1));
            } else {
                p = in1 + (size_t)g * K1 + k0 + kk;
            }
            float4 a = *(const float4*)p, bq = *(const float4*)(p + 4);
            float sv[8] = {a.x, a.y, a.z, a.w, bq.x, bq.y, bq.z, bq.w};
            U8 hi, lo;
#pragma unroll
            for (int i = 0; i < 8; i++) {
                ushort hh = f2bf(sv[i]);
                hi.s[i] = (short)hh;
                lo.s[i] = (short)f2bf(sv[i] - bfbits2f(hh));
            }
            *(s8b*)&Xhi[row][kk] = hi.v;
            *(s8b*)&Xlo[row][kk] = lo.v;
        }
        {   // W tile: CB*4 s8b-chunks, strided over 512 threads
            for (int id = t; id < CB * 4; id += 512) {
                int cc = id >> 2, kk = (id & 3) * 8;
                size_t gsrc = (size_t)(c0 + cc) * KD + k0 + kk;
                *(s8b*)&Whi[cc][kk] = *(const s8b*)&WT_hi[gsrc];
                *(s8b*)&Wlo[cc][kk] = *(const s8b*)&WT_lo[gsrc];
            }
        }
        __syncthreads();

        s8b ah0 = *(const s8b*)&Xhi[32 * rh + c][quad * 8];
        s8b al0 = *(const s8b*)&Xlo[32 * rh + c][quad * 8];
        s8b ah1 = *(const s8b*)&Xhi[32 * rh + 16 + c][quad * 8];
        s8b al1 = *(const s8b*)&Xlo[32 * rh + 16 + c][quad * 8];
#pragma unroll
        for (int ct = 0; ct < NCH; ct++) {
            s8b bh = *(const s8b*)&Whi[ch * (CB / 2) + ct * 16 + c][quad * 8];
            s8b bl = *(const s8b*)&Wlo[ch * (CB / 2) + ct * 16 + c][quad * 8];
            acc[0][ct] = __builtin_amdgcn_mfma_f32_16x16x32_bf16(ah0, bh, acc[0][ct], 0, 0, 0);
            acc[0][ct] = __builtin_amdgcn_mfma_f32_16x16x32_bf16(al0, bh, acc[0][ct], 0, 0, 0);
            acc[0][ct] = __builtin_amdgcn_mfma_f32_16x16x32_bf16(ah0, bl, acc[0][ct], 0, 0, 0);
            acc[1][ct] = __builtin_amdgcn_mfma_f32_16x16x32_bf16(ah1, bh, acc[1][ct], 0, 0, 0);
            acc[1][ct] = __builtin_amdgcn_mfma_f32_16x16x32_bf16(al1, bh, acc[1][ct], 0, 0, 0);
            acc[1][ct] = __builtin_amdgcn_mfma_f32_16x16x32_bf16(ah1, bl, acc[1][ct], 0, 0, 0);
        }
    }

    if (OMODE == 3) {
        float fc[2][2][4];
#pragma unroll
        for (int st = 0; st < 2; st++)
#pragma unroll
            for (int o = 0; o < 2; o++)
#pragma unroll
                for (int r = 0; r < 4; r++) fc[st][o][r] = 0.f;
#pragma unroll
        for (int ct = 0; ct < NCH; ct++) {
            const int col = c0 + ch * (CB / 2) + ct * 16 + c;
            float bv = bias[col];
            float w0 = Wfin[col * 2], w1 = Wfin[col * 2 + 1];
#pragma unroll
            for (int st = 0; st < 2; st++) {
                const int rg = r0 + 32 * rh + 16 * st + quad * 4;
#pragma unroll
                for (int r = 0; r < 4; r++) {
                    float v = acc[st][ct][r] + bv;
                    if (RELU) v = fmaxf(v, 0.f);
                    if (RESID) v += out[(size_t)(rg + r) * 128 + col];
                    fc[st][0][r] += v * w0;
                    fc[st][1][r] += v * w1;
                }
            }
        }
#pragma unroll
        for (int st = 0; st < 2; st++)
#pragma unroll
            for (int r = 0; r < 4; r++) {
                float a0 = fc[st][0][r], a1 = fc[st][1][r];
#pragma unroll
                for (int off = 1; off < 16; off <<= 1) {
                    a0 += __shfl_xor(a0, off, 16);
                    a1 += __shfl_xor(a1, off, 16);
                }
                fc[st][0][r] = a0; fc[st][1][r] = a1;
            }
        if (ch == 1 && c == 0) {
#pragma unroll
            for (int st = 0; st < 2; st++)
#pragma unroll
                for (int r = 0; r < 4; r++) {
                    int lr = 32 * rh + 16 * st + quad * 4 + r;
                    red[lr][0] = fc[st][0][r];
                    red[lr][1] = fc[st][1][r];
                }
        }
        __syncthreads();
        if (ch == 0 && c == 0) {
#pragma unroll
            for (int st = 0; st < 2; st++)
#pragma unroll
                for (int r = 0; r < 4; r++) {
                    int lr = 32 * rh + 16 * st + quad * 4 + r;
                    size_t row = (size_t)r0 + lr;
                    fout[row * 2]     = fc[st][0][r] + red[lr][0] + bfin[0];
                    fout[row * 2 + 1] = fc[st][1][r] + red[lr][1] + bfin[1];
                }
        }
        return;
    }
#pragma unroll
    for (int st = 0; st < 2; st++) {
        const int row_g0 = r0 + 32 * rh + 16 * st + quad * 4;
#pragma unroll
        for (int ct = 0; ct < NCH; ct++) {
            const int col = c0 + ch * (CB / 2) + ct * 16 + c;
            if (OMODE == 1) {
                int tensor = col >> 7, cc2 = col & 127;
                float bv = (tensor == 0 ? bias : tensor == 1 ? biask : biasv)[cc2];
                int head = cc2 >> 6, d = cc2 & 63;
                int b = row_g0 >> 10, n = row_g0 & 1023;
                if (tensor == 2) {
                    // V^T [B,H,64,N]: 4 consecutive n -> one 8B packed store
                    U4 pk;
#pragma unroll
                    for (int r = 0; r < 4; r++) pk.s[r] = (short)f2bf(acc[st][ct][r] + bv);
                    size_t addr = (((size_t)b * HEADS + head) * 64 + d) * NN + n;
                    *(s4b*)&outq[2 * SZQ + addr] = pk.v;
                } else {
                    ushort* dst = outq + (size_t)tensor * SZQ
                                + (((size_t)b * HEADS + head) * NN + n) * 64 + d;
#pragma unroll
                    for (int r = 0; r < 4; r++) dst[(size_t)r * 64] = f2bf(acc[st][ct][r] + bv);
                }
            } else {
                float bv = bias[col];
#pragma unroll
                for (int r = 0; r < 4; r++) {
                    float v = acc[st][ct][r] + bv;
                    if (RELU) v = fmaxf(v, 0.f);
                    size_t o = (size_t)(row_g0 + r) * 128 + col;
                    if (RESID) v += out[o];
                    out[o] = v;
                }
            }
        }
    }
}

// ---------------------------------------------------------------------------
// R13 MFMA flash attention: 128 Q-rows per block (8 waves, 512 threads).
// K/V staging per 128-key stage now serves 2x the Q rows; per-bh panel
// re-reads halve. XCD swizzle keeps the 8 blocks per bh on one XCD.
// ---------------------------------------------------------------------------
__global__ __launch_bounds__(512) void attn_mfma_kernel(const ushort* __restrict__ q,
                                                        const ushort* __restrict__ k,
                                                        const ushort* __restrict__ vt,
                                                        float* __restrict__ ctx) {
    __shared__ short Ks[128][72];
    __shared__ short Vt[64][136];

    // bijective XCD swizzle: 512 blocks = 8 xcd * 8 bh-per-xcd * 8 n0
    const int bidx = blockIdx.x;
    const int u  = bidx >> 3;
    const int bh = (bidx & 7) + 8 * (u >> 3);
    const int n0 = (u & 7) * 128;
    const int b  = bh >> 1, h = bh & 1;
    const int t  = threadIdx.x;
    const int w  = t >> 6;               // 8 waves x 16 rows = 128 rows
    const int lane = t & 63;
    const int quad = lane >> 4, c = lane & 15;
    const size_t kvbase = (size_t)bh * NN * 64;   // same elem count for k and vt
    const float scale = 0.125f;

    s8b qf0, qf1;
    {
        const ushort* qrow = q + kvbase + (size_t)(n0 + 16 * w + c) * 64;
        qf0 = *(const s8b*)(qrow + quad * 8);
        qf1 = *(const s8b*)(qrow + 32 + quad * 8);
    }

    f4 O[4];
#pragma unroll
    for (int i = 0; i < 4; i++) O[i] = (f4){0.f, 0.f, 0.f, 0.f};
    float l_i = 0.f;

    for (int kt0 = 0; kt0 < NN; kt0 += 128) {
        __syncthreads();
        {   // K: 128 keys x 64 d, 2 b128 per thread (512 threads)
            int key = t >> 2, d0 = (t & 3) * 16;
            const ushort* kr = k + kvbase + (size_t)(kt0 + key) * 64 + d0;
            *(s8b*)&Ks[key][d0]     = *(const s8b*)kr;
            *(s8b*)&Ks[key][d0 + 8] = *(const s8b*)(kr + 8);
            // V^T: 64 d-rows x 128 cols, 2 b128 per thread
            int d = t >> 3, chv = (t & 7) * 16;
            const ushort* vr = vt + kvbase + (size_t)d * NN + kt0 + chv;
            *(s8b*)&Vt[d][chv]     = *(const s8b*)vr;
            *(s8b*)&Vt[d][chv + 8] = *(const s8b*)(vr + 8);
        }
        __syncthreads();

        // ---- S for 4 groups of 32 keys ----
        f4 sg[4][2];
#pragma unroll
        for (int g = 0; g < 4; g++) {
            const int kb = g * 32;
            sg[g][0] = (f4){0.f, 0.f, 0.f, 0.f};
            sg[g][1] = (f4){0.f, 0.f, 0.f, 0.f};
#pragma unroll
            for (int ch = 0; ch < 2; ch++) {
                s8b ka = *(const s8b*)&Ks[kb + c][ch * 32 + quad * 8];
                s8b kB = *(const s8b*)&Ks[kb + 16 + c][ch * 32 + quad * 8];
                s8b qf = ch ? qf1 : qf0;
                sg[g][0] = __builtin_amdgcn_mfma_f32_16x16x32_bf16(ka, qf, sg[g][0], 0, 0, 0);
                sg[g][1] = __builtin_amdgcn_mfma_f32_16x16x32_bf16(kB, qf, sg[g][1], 0, 0, 0);
            }
        }
        // ---- softmax numerator without running max ----
        float pv[4][8];
        float ps = 0.f;
#pragma unroll
        for (int g = 0; g < 4; g++)
#pragma unroll
            for (int r = 0; r < 4; r++) {
                pv[g][r]     = __expf(sg[g][0][r] * scale);
                pv[g][4 + r] = __expf(sg[g][1][r] * scale);
                ps += pv[g][r] + pv[g][4 + r];
            }
        ps += __shfl_xor(ps, 16);
        ps += __shfl_xor(ps, 32);
        l_i += ps;

        // ---- P transpose + PV per group ----
        int addr0 = ((((2 * quad) & 3) << 4) | c) << 2;
        int addr1 = ((((2 * quad + 1) & 3) << 4) | c) << 2;
        int tsel = quad >> 1;
#pragma unroll
        for (int g = 0; g < 4; g++) {
            const int kb = g * 32;
            uint Da01 = pk_bf16(pv[g][0], pv[g][1]), Da23 = pk_bf16(pv[g][2], pv[g][3]);
            uint Db01 = pk_bf16(pv[g][4], pv[g][5]), Db23 = pk_bf16(pv[g][6], pv[g][7]);
            int A01_0 = __builtin_amdgcn_ds_bpermute(addr0, (int)Da01);
            int A23_0 = __builtin_amdgcn_ds_bpermute(addr0, (int)Da23);
            int B01_0 = __builtin_amdgcn_ds_bpermute(addr0, (int)Db01);
            int B23_0 = __builtin_amdgcn_ds_bpermute(addr0, (int)Db23);
            int A01_1 = __builtin_amdgcn_ds_bpermute(addr1, (int)Da01);
            int A23_1 = __builtin_amdgcn_ds_bpermute(addr1, (int)Da23);
            int B01_1 = __builtin_amdgcn_ds_bpermute(addr1, (int)Db01);
            int B23_1 = __builtin_amdgcn_ds_bpermute(addr1, (int)Db23);
            union { int i[4]; s8b s; } pf;
            pf.i[0] = tsel ? B01_0 : A01_0;
            pf.i[1] = tsel ? B23_0 : A23_0;
            pf.i[2] = tsel ? B01_1 : A01_1;
            pf.i[3] = tsel ? B23_1 : A23_1;
#pragma unroll
            for (int dt = 0; dt < 4; dt++) {
                s8b vf = *(const s8b*)&Vt[16 * dt + c][kb + quad * 8];
                O[dt] = __builtin_amdgcn_mfma_f32_16x16x32_bf16(vf, pf.s, O[dt], 0, 0, 0);
            }
        }
    }

    float inv = 1.0f / l_i;
    float* crow = ctx + ((size_t)b * NN + n0 + 16 * w + c) * HIDD + h * DH;
#pragma unroll
    for (int dt = 0; dt < 4; dt++)
#pragma unroll
        for (int r = 0; r < 4; r++)
            crow[16 * dt + 4 * quad + r] = O[dt][r] * inv;
}

// ---------------------------------------------------------------------------
extern "C" void kernel_launch(void* const* d_in, const int* in_sizes, int n_in,
                              void* d_out, int out_size, void* d_ws, size_t ws_size,
                              hipStream_t stream) {
    (void)in_sizes; (void)n_in; (void)out_size; (void)ws_size;
    const float* X     = (const float*)d_in[0];
    const float* A     = (const float*)d_in[1];
    const float* T     = (const float*)d_in[2];
    const float* theta = (const float*)d_in[3];
    const float* W_raw = (const float*)d_in[4];
    const float* b_raw = (const float*)d_in[5];
    const float* Wd0   = (const float*)d_in[6];
    const float* bd0   = (const float*)d_in[7];
    const float* Wd1   = (const float*)d_in[8];
    const float* bd1   = (const float*)d_in[9];
    const float* W_fin = (const float*)d_in[10];
    const float* b_fin = (const float*)d_in[11];
    const float* Wq0 = (const float*)d_in[12]; const float* bq0 = (const float*)d_in[13];
    const float* Wk0 = (const float*)d_in[14]; const float* bk0 = (const float*)d_in[15];
    const float* Wv0 = (const float*)d_in[16]; const float* bv0 = (const float*)d_in[17];
    const float* Wo0 = (const float*)d_in[18]; const float* bo0 = (const float*)d_in[19];
    const float* Wq1 = (const float*)d_in[20]; const float* bq1 = (const float*)d_in[21];
    const float* Wk1 = (const float*)d_in[22]; const float* bk1 = (const float*)d_in[23];
    const float* Wv1 = (const float*)d_in[24]; const float* bv1 = (const float*)d_in[25];
    const float* Wo1 = (const float*)d_in[26]; const float* bo1 = (const float*)d_in[27];

    float* ws   = (float*)d_ws;
    const size_t SZ = (size_t)BB * NN * HIDD;
    ushort* Q0hi = (ushort*)ws;
    ushort* Q0lo = Q0hi + (size_t)NN * NN;
    float* hp   = ws + (size_t)NN * NN;
    float* h    = hp + SZ;
    float* z    = h + SZ;
    ushort* qb  = (ushort*)(z + SZ);          // q | k | v^T contiguous (3*SZ)
    ushort* kb  = qb + SZ;
    ushort* XT_hi = qb + 3 * SZ;
    ushort* XT_lo = XT_hi + SZ / 2;
    ushort* hT_hi = XT_lo + SZ / 2;
    ushort* hT_lo = hT_hi + SZ;
    ushort* WT_hi = hT_lo + SZ;
    ushort* WT_lo = WT_hi + 262144;
    ushort* Q1hi = WT_lo + 262144;
    ushort* Q1lo = Q1hi + (size_t)NN * NN;

    const int OFF_RAW = 0, OFF_D0 = 8192, OFF_D1 = 16384, OFF_QKV0 = 32768,
              OFF_O0 = 131072, OFF_QKV1 = 147456, OFF_O1 = 245760;

    const int attnGrid = BB * HEADS * (NN / 128);   // 512
    const int diffGrid = BB * (NN / 64);            // 512
    const dim3 dg1(256, 1);                         // 128-row dense blocks

    // fused prep_w + X transpose/split + build_q layers 0 AND 1
    setup_kernel<<<2560, 256, 0, stream>>>(W_raw, Wd0, Wd1, Wq0, Wk0, Wv0, Wo0,
                                           Wq1, Wk1, Wv1, Wo1, WT_hi, WT_lo,
                                           T, theta, Q0hi, Q0lo, Q1hi, Q1lo,
                                           X, XT_hi, XT_lo);

    // ---- layer 0 ----
    dense_mfma_kernel<64, 0, 128, false, false, 0><<<dg1, 512, 0, stream>>>(
        X, nullptr, WT_hi + OFF_RAW, WT_lo + OFF_RAW, b_raw, nullptr, nullptr,
        hp, nullptr, nullptr, nullptr, nullptr);
    diff_dense_kernel<64, true><<<diffGrid, 512, 0, stream>>>(
        Q0hi, Q0lo, A, XT_hi, XT_lo, WT_hi + OFF_D0, WT_lo + OFF_D0, bd0,
        h, hT_hi, hT_lo);
    dense_mfma_kernel<128, 128, 192, false, false, 1><<<512, 512, 0, stream>>>(
        h, hp, WT_hi + OFF_QKV0, WT_lo + OFF_QKV0, bq0, bk0, bv0,
        nullptr, qb, nullptr, nullptr, nullptr);
    attn_mfma_kernel<<<attnGrid, 512, 0, stream>>>(qb, kb, qb + 2 * SZ, z);
    dense_mfma_kernel<128, 0, 128, true, false, 0><<<dg1, 512, 0, stream>>>(
        z, nullptr, WT_hi + OFF_O0, WT_lo + OFF_O0, bo0, nullptr, nullptr,
        hp, nullptr, nullptr, nullptr, nullptr);

    // ---- layer 1 ----
    diff_dense_kernel<128, false><<<diffGrid, 512, 0, stream>>>(
        Q1hi, Q1lo, A, hT_hi, hT_lo, WT_hi + OFF_D1, WT_lo + OFF_D1, bd1,
        h, nullptr, nullptr);
    dense_mfma_kernel<128, 128, 192, false, false, 1><<<512, 512, 0, stream>>>(
        h, hp, WT_hi + OFF_QKV1, WT_lo + OFF_QKV1, bq1, bk1, bv1,
        nullptr, qb, nullptr, nullptr, nullptr);
    attn_mfma_kernel<<<attnGrid, 512, 0, stream>>>(qb, kb, qb + 2 * SZ, z);
    dense_mfma_kernel<128, 0, 128, true, true, 3><<<dg1, 512, 0, stream>>>(
        z, nullptr, WT_hi + OFF_O1, WT_lo + OFF_O1, bo1, nullptr, nullptr,
        hp, nullptr, W_fin, b_fin, (float*)d_out);
}